// Round 14
// baseline (355.917 us; speedup 1.0000x reference)
//
#include <hip/hip_runtime.h>
#include <cstdint>

// ---------------- geometry ----------------
constexpr int BB = 2, C = 64;
constexpr int D1 = 31;          // conv1 out / conv2,3 spatial
constexpr int DP = 33;          // padded spatial for x1..x3
constexpr int D4 = 63;          // conv_transpose out spatial
constexpr int D5 = 61;          // conv5 out spatial
constexpr int D5CUBE = D5*D5*D5;   // 226981

constexpr int NV1 = BB*D1*D1*D1;   // 59582
constexpr int NVP = BB*DP*DP*DP;   // 71874
constexpr int NV4 = BB*D4*D4*D4;   // 500094
constexpr int NV5 = BB*D5*D5*D5;   // 453962

// ---------------- workspace layout (byte offsets) ----------------
constexpr size_t alup(size_t x) { return (x + 255) & ~(size_t)255; }
constexpr size_t OB_X0  = 0;                                     // [NVP][3] f32
constexpr size_t OB_M0  = alup(OB_X0  + (size_t)NVP*3*4);        // [NVP] f32
constexpr size_t OB_M1P = alup(OB_M0  + (size_t)NVP*4);          // [NVP] f32 padded mask
constexpr size_t OB_X1  = alup(OB_M1P + (size_t)NVP*4);          // [NVP][64] bf16 padded
constexpr size_t OB_X2  = alup(OB_X1  + (size_t)NVP*64*2);       // [NVP][64] bf16 padded
constexpr size_t OB_X3  = alup(OB_X2  + (size_t)NVP*64*2);       // [NVP][64] bf16 padded
constexpr size_t OB_MT  = alup(OB_X3  + (size_t)NVP*64*2);       // [NV4] f32 (fully rewritten)
constexpr size_t OB_X4  = alup(OB_MT  + (size_t)NV4*4);          // [NV4][64] bf16 (fully rewritten)
constexpr size_t OB_WB2 = alup(OB_X4  + (size_t)NV4*64*2);
constexpr size_t OB_WB3 = alup(OB_WB2 + (size_t)27*64*64*2);
constexpr size_t OB_WBT = alup(OB_WB3 + (size_t)27*64*64*2);
constexpr size_t OB_WB5 = alup(OB_WBT + (size_t)27*64*64*2);

// ---------------- types / helpers ----------------
typedef __attribute__((ext_vector_type(8))) short short8;
typedef __attribute__((ext_vector_type(4))) float f32x4;

__device__ inline unsigned short f2bf(float f) {
  unsigned int u = __float_as_uint(f);
  u = (u + 0x7FFFu + ((u >> 16) & 1u)) >> 16;   // RNE
  return (unsigned short)u;
}

template<int DD>
__device__ inline void decodev(int vox, int& b, int& z, int& y, int& x) {
  x = vox % DD; int r = vox / DD;
  y = r % DD;   r /= DD;
  z = r % DD;   b = r / DD;
}

// bijective XCD-chunked block swizzle (m204)
__device__ inline int xcd_swz(int bid, int nb) {
  int q = nb >> 3, r = nb & 7;
  int xcd = bid & 7, idx = bid >> 3;
  return (xcd < r ? xcd*(q+1) : r*(q+1) + (xcd - r)*q) + idx;
}

// ---------------- per-launch zero init ----------------
__global__ void __launch_bounds__(256)
k_zero(float* __restrict__ x0, float* __restrict__ m0, float* __restrict__ m1p,
       unsigned short* __restrict__ x1, unsigned short* __restrict__ x2,
       unsigned short* __restrict__ x3) {
  int v = blockIdx.x*256 + threadIdx.x;
  if (v >= NVP) return;
  m0[v] = 0.f; m1p[v] = 0.f;
  x0[3*v+0] = 0.f; x0[3*v+1] = 0.f; x0[3*v+2] = 0.f;
  int x = v % DP, r = v / DP;
  int y = r % DP; r /= DP;
  int z = r % DP;
  if (x==0 || x==DP-1 || y==0 || y==DP-1 || z==0 || z==DP-1) {
    ulonglong2 zz = {0ull, 0ull};
    ulonglong2* p1 = (ulonglong2*)(x1 + (size_t)v*64);
    ulonglong2* p2 = (ulonglong2*)(x2 + (size_t)v*64);
    ulonglong2* p3 = (ulonglong2*)(x3 + (size_t)v*64);
    #pragma unroll
    for (int i = 0; i < 8; i++) { p1[i] = zz; p2[i] = zz; p3[i] = zz; }
  }
}

// ---------------- scatter ----------------
__global__ void k_scatter(const float* __restrict__ feat, const int* __restrict__ coors,
                          int n, float* __restrict__ x0, float* __restrict__ m0) {
  int i = blockIdx.x*blockDim.x + threadIdx.x;
  if (i >= n) return;
  int b = coors[4*i+0], z = coors[4*i+1], y = coors[4*i+2], x = coors[4*i+3];
  int v = ((b*DP + z)*DP + y)*DP + x;
  x0[v*3+0] = feat[3*i+0];
  x0[v*3+1] = feat[3*i+1];
  x0[v*3+2] = feat[3*i+2];
  m0[v] = 1.0f;
}

// ---------------- conv1: 3 -> 64, VALID, mask+act, bf16 out ----------------
__global__ void __launch_bounds__(256)
k_conv1(const float* __restrict__ x0, const float* __restrict__ m0,
        unsigned short* __restrict__ x1, float* __restrict__ m1p,
        const float* __restrict__ w1, const float* __restrict__ b1,
        const float* __restrict__ s1, const float* __restrict__ h1) {
  long long t = (long long)blockIdx.x*blockDim.x + threadIdx.x;
  if (t >= (long long)NV1*C) return;
  int co  = (int)(t & 63);
  int vox = (int)(t >> 6);
  int b, z, y, x; decodev<D1>(vox, b, z, y, x);
  float sum = 0.f, mm = 0.f;
  #pragma unroll
  for (int kz=0; kz<3; kz++)
  #pragma unroll
  for (int ky=0; ky<3; ky++)
  #pragma unroll
  for (int kx=0; kx<3; kx++) {
    int iv = ((b*DP + z+kz)*DP + y+ky)*DP + (x+kx);
    mm += m0[iv];
    const float* px = x0 + iv*3;
    const float* pw = w1 + ((kz*3+ky)*3+kx)*3*64 + co;
    sum += px[0]*pw[0] + px[1]*pw[64] + px[2]*pw[128];
  }
  bool m = mm > 0.f;
  float o = m ? fmaxf((sum + b1[co])*s1[co] + h1[co], 0.f) : 0.f;
  size_t pOff = (size_t)(((b*DP + z+1)*DP + y+1)*DP + (x+1));
  x1[pOff*C + co] = f2bf(o);
  if (co == 0) m1p[pOff] = m ? 1.f : 0.f;
}

// ---------------- fused weight repack (4 arrays) into MFMA fragment lane order ----------------
__global__ void k_repack4(const float* __restrict__ wa, const float* __restrict__ wb,
                          const float* __restrict__ wc, const float* __restrict__ wd,
                          unsigned short* __restrict__ da, unsigned short* __restrict__ db,
                          unsigned short* __restrict__ dc, unsigned short* __restrict__ dd) {
  int which = blockIdx.x / 432;
  int i = (blockIdx.x - which*432)*256 + threadIdx.x;
  const float* w = which == 0 ? wa : which == 1 ? wb : which == 2 ? wc : wd;
  unsigned short* dst = which == 0 ? da : which == 1 ? db : which == 2 ? dc : dd;
  int co = i & 63, k = (i >> 6) & 63, t = i >> 12;
  int kk = k >> 5, q = (k >> 3) & 3, j = k & 7, cb = co >> 4, l = q*16 + (co & 15);
  dst[(size_t)((t*2+kk)*4+cb)*512 + l*8 + j] = f2bf(w[i]);
}

// ---------------- mT mask precompute ----------------
__global__ void __launch_bounds__(256)
k_maskT(const float* __restrict__ m1p, float* __restrict__ mt) {
  int vox = blockIdx.x*256 + threadIdx.x;
  if (vox >= NV4) return;
  int b, zo, yo, xo; decodev<D4>(vox, b, zo, yo, xo);
  float mm = 0.f;
  for (int kz = 0; kz < 3; kz++) {
    if ((zo + kz) & 1) continue;
    int izp = ((zo + kz - 2) >> 1) + 1;
    for (int ky = 0; ky < 3; ky++) {
      if ((yo + ky) & 1) continue;
      int iyp = ((yo + ky - 2) >> 1) + 1;
      for (int kx = 0; kx < 3; kx++) {
        if ((xo + kx) & 1) continue;
        int ixp = ((xo + kx - 2) >> 1) + 1;
        mm += m1p[((b*DP + izp)*DP + iyp)*DP + ixp];
      }
    }
  }
  mt[vox] = mm;
}

__device__ __forceinline__ void c_step2(const short8 (&A)[2], const short8 (&W)[4],
                                        f32x4 (&acc)[2][4]) {
  #pragma unroll
  for (int a = 0; a < 2; a++)
    #pragma unroll
    for (int cb = 0; cb < 4; cb++)
      acc[a][cb] = __builtin_amdgcn_mfma_f32_16x16x32_bf16(W[cb], A[a], acc[a][cb], 0, 0, 0);
}

// ---------------- conv2/3: staged 9-phase SAME conv on padded 33^3 grid ----------------
// Block = 4 waves = out rows (b, z, y0..y0+3) x 31 x, 64 co.  Phase (kz,ky):
// stage 4 padded rows (33 vox x 128B, XOR chunk swizzle, padded to 1280 chunks)
// for phase p+1 while computing 6 steps (kx,kk) from the current half.
constexpr int C23_HALF = 1280;    // 1056 real chunks + pad (5*256 dst slots)

__global__ void __launch_bounds__(256)
k_conv23_mfma(const unsigned short* __restrict__ xin, const unsigned short* __restrict__ wB,
              unsigned short* __restrict__ xout, const float* __restrict__ m1p,
              const float* __restrict__ bias, const float* __restrict__ s,
              const float* __restrict__ h) {
  __shared__ short8 sA[2*C23_HALF];
  const int tid  = threadIdx.x;
  const int lane = tid & 63;
  const int wid  = tid >> 6;
  const int ll   = lane & 15;
  const int l16  = lane >> 4;

  const int blk = xcd_swz(blockIdx.x, gridDim.x);
  const int yt  = blk & 7;                 // 8 y-tiles of 4 rows
  const int rzb = blk >> 3;
  const int z   = rzb % D1;
  const int b   = rzb / D1;
  const int y0  = yt * 4;

  // stage geometry: block-wide chunk g = it*256+tid -> (row r, vox v, swz c16)
  int st_r[5], st_base[5];
  #pragma unroll
  for (int it = 0; it < 5; ++it) {
    int g = it*256 + tid; g = g > 1055 ? 1055 : g;   // 1056 = 4 rows * 264
    int r = g / 264, rem = g - r*264;
    int v = rem >> 3, c16p = rem & 7;
    int c16l = c16p ^ (v & 7);
    st_r[it] = r;
    st_base[it] = (v << 7) + (c16l << 4);
  }

  const char* xinb = (const char*)xin;

  f32x4 acc[2][4];
  #pragma unroll
  for (int a = 0; a < 2; a++)
    #pragma unroll
    for (int cb = 0; cb < 4; cb++)
      acc[a][cb] = f32x4{0.f, 0.f, 0.f, 0.f};

  auto STAGE = [&](int kzn, int kyn, int hn) {
    size_t pb = (size_t)((b*DP + z + kzn)*DP) * (DP*128);
    char* dst = (char*)&sA[0] + hn*(C23_HALF*16);
    #pragma unroll
    for (int it = 0; it < 5; ++it) {
      int yin = y0 + st_r[it] + kyn; yin = yin > 32 ? 32 : yin;
      __builtin_amdgcn_global_load_lds(
        (const __attribute__((address_space(1))) void*)(xinb + pb + (size_t)yin*(DP*128) + st_base[it]),
        (__attribute__((address_space(3))) void*)(dst + it*4096 + wid*1024),
        16, 0, 0);
    }
  };
  auto LDA = [&](int hh, int kx, int kk, short8 (&A)[2]) {
    #pragma unroll
    for (int a = 0; a < 2; a++) {
      int xv = a*16 + ll; xv = xv > 30 ? 30 : xv;   // x=31 duplicated, discarded
      int v  = xv + kx;
      int ch = hh*C23_HALF + wid*264 + v*8 + ((kk*4 + l16) ^ (v & 7));
      A[a] = sA[ch];
    }
  };

  short8 A0[2], A1[2];

  STAGE(0, 0, 0);
  __syncthreads();

  int kzn = 0, kyn = 1;
  #pragma unroll 1
  for (int p = 0; p < 9; ++p) {
    const int hh = p & 1;

    short8 W[6][4];
    {
      const unsigned short* wp = wB + (size_t)p*12288 + lane*8;
      #pragma unroll
      for (int st = 0; st < 6; ++st)
        #pragma unroll
        for (int cb = 0; cb < 4; cb++)
          W[st][cb] = *reinterpret_cast<const short8*>(wp + st*2048 + cb*512);
    }
    __builtin_amdgcn_sched_barrier(0);

    if (p < 8) {
      STAGE(kzn, kyn, hh ^ 1);
      kyn++; if (kyn == 3) { kyn = 0; kzn++; }
    }
    __builtin_amdgcn_sched_barrier(0);

    LDA(hh, 0, 0, A0);
    #pragma unroll
    for (int st = 0; st < 6; ++st) {
      const int kxn = (st+1) >> 1, kkn = (st+1) & 1;
      if (st < 5) {
        if (st & 1) LDA(hh, kxn, kkn, A0); else LDA(hh, kxn, kkn, A1);
      }
      if (st & 1) c_step2(A1, W[st], acc); else c_step2(A0, W[st], acc);
    }
    __syncthreads();
  }

  // epilogue: D row = co = cb*16+l16*4+r, col = x = a*16+ll; packed 8B stores
  const int y = y0 + wid;
  if (y < D1) {
    #pragma unroll
    for (int a = 0; a < 2; a++) {
      int x = a*16 + ll;
      if (x >= D1) continue;
      size_t pOff = (size_t)(((b*DP + z+1)*DP + y+1)*DP + (x+1));
      bool m = m1p[pOff] > 0.f;
      #pragma unroll
      for (int cb = 0; cb < 4; cb++) {
        unsigned long long pack = 0;
        #pragma unroll
        for (int r = 0; r < 4; r++) {
          int co = cb*16 + l16*4 + r;
          float o = m ? fmaxf((acc[a][cb][r] + bias[co])*s[co] + h[co], 0.f) : 0.f;
          pack |= (unsigned long long)f2bf(o) << (16*r);
        }
        *reinterpret_cast<unsigned long long*>(xout + pOff*64 + cb*16 + l16*4) = pack;
      }
    }
  }
}

// ---------------- convT v2: single-shot LDS-staged parity-decomposed MFMA ----------------
constexpr int CT_CHUNKS = 1792;   // 7 iters * 256 threads; 1584 used + pad

__global__ void __launch_bounds__(256)
k_convT_mfma(const unsigned short* __restrict__ x3, const unsigned short* __restrict__ wB,
             unsigned short* __restrict__ x4, const float* __restrict__ mt,
             const float* __restrict__ bias, const float* __restrict__ s,
             const float* __restrict__ h) {
  __shared__ short8 sb[CT_CHUNKS];
  const int tid  = threadIdx.x;
  const int lane = tid & 63;
  const int wid  = tid >> 6;
  const int ii   = lane & 15;
  const int l16  = lane >> 4;

  const int blk   = xcd_swz(blockIdx.x, gridDim.x);
  const int ytile = blk & 15;
  const int rzb   = blk >> 4;
  const int zo    = rzb % D4;
  const int b     = rzb / D4;
  const int y0    = ytile * 4;

  const int izp0 = (zo + (zo & 1)) >> 1;
  const int izp1 = (zo & 1) ? izp0 : izp0 + 1;

  #pragma unroll
  for (int it = 0; it < 7; ++it) {
    int g = it*256 + tid; g = g > 1583 ? 1583 : g;
    int r6 = g / 264, rem = g - r6*264;
    int v = rem >> 3, c16p = rem & 7;
    int c16l = c16p ^ (v & 7);
    int pz  = r6 >= 3 ? 1 : 0;
    int ry  = r6 - pz*3;
    int izp = pz ? izp1 : izp0;
    int iyp = ytile*2 + ry;
    size_t srcB = ((size_t)((b*DP + izp)*DP + iyp)*DP)*128 + (size_t)(v << 7) + (c16l << 4);
    __builtin_amdgcn_global_load_lds(
      (const __attribute__((address_space(1))) void*)((const char*)x3 + srcB),
      (__attribute__((address_space(3))) void*)((char*)&sb[0] + it*4096 + wid*1024),
      16, 0, 0);
  }
  __syncthreads();

  f32x4 acc[4][4];
  #pragma unroll
  for (int a = 0; a < 4; a++)
    #pragma unroll
    for (int cb = 0; cb < 4; cb++)
      acc[a][cb] = f32x4{0.f, 0.f, 0.f, 0.f};

  const int yo = y0 + wid;
  if (yo < D4) {
    const int nPz = (zo & 1) ? 1 : 2;
    #pragma unroll 1
    for (int pz = 0; pz < 2; ++pz) {
      if (pz >= nPz) break;
      const int kz = (zo & 1) ? 1 : pz*2;
      #pragma unroll 1
      for (int kyi = 0; kyi < 2; ++kyi) {
        int ky, ry;
        if (wid & 1) { if (kyi == 1) break; ky = 1; ry = (wid + 1) >> 1; }
        else         { ky = kyi*2;          ry = (wid >> 1) + kyi; }
        const int rbase = (pz*3 + ry)*264;
        #pragma unroll
        for (int kx = 0; kx < 3; ++kx) {
          const int apar  = kx & 1;
          const int xoffE = ((kx + apar - 2) >> 1) + 1;
          const int t = (kz*3 + ky)*3 + kx;
          #pragma unroll
          for (int kk = 0; kk < 2; ++kk) {
            short8 Bv[4];
            const unsigned short* wpk = wB + (size_t)(t*2+kk)*2048 + lane*8;
            #pragma unroll
            for (int cb = 0; cb < 4; cb++)
              Bv[cb] = *reinterpret_cast<const short8*>(wpk + cb*512);
            #pragma unroll
            for (int ablk = 0; ablk < 2; ablk++) {
              const int ixp = ablk*16 + ii + xoffE;
              short8 A = sb[rbase + ixp*8 + ((kk*4 + l16) ^ (ixp & 7))];
              const int afr = apar*2 + ablk;
              #pragma unroll
              for (int cb = 0; cb < 4; cb++)
                acc[afr][cb] = __builtin_amdgcn_mfma_f32_16x16x32_bf16(A, Bv[cb], acc[afr][cb], 0, 0, 0);
            }
          }
        }
      }
    }

    float bv[4], sv[4], hv[4];
    #pragma unroll
    for (int cb = 0; cb < 4; cb++) {
      int c = cb*16 + (lane & 15);
      bv[cb] = bias[c]; sv[cb] = s[c]; hv[cb] = h[c];
    }
    const int rowBase = ((b*D4 + zo)*D4 + yo)*D4;
    #pragma unroll
    for (int a = 0; a < 4; a++) {
      const int ablk = a & 1, apar = a >> 1;
      #pragma unroll
      for (int r = 0; r < 4; r++) {
        const int row = (lane >> 4)*4 + r;
        const int xo  = 2*(ablk*16 + row) + apar;
        if (xo >= D4) continue;
        const int vox = rowBase + xo;
        const bool m = mt[vox] > 0.f;
        #pragma unroll
        for (int cb = 0; cb < 4; cb++) {
          float o = m ? fmaxf((acc[a][cb][r] + bv[cb])*sv[cb] + hv[cb], 0.f) : 0.f;
          x4[(size_t)vox*64 + cb*16 + (lane & 15)] = f2bf(o);
        }
      }
    }
  }
}

// ---------------- conv5 v11: x-tiled 40KB LDS (4 blocks/CU target), default bounds ----------------
// Block = 4 waves = out rows (b, z, y0..y0+3) x 32 out-x (xtile), 64 co.
// Same 9-phase pipeline as v10 but per-phase tile = 4 rows x 40 vox (20KB halves).
// v7's regression was __launch_bounds__(256,4) forcing VGPR=64; default bounds
// keep VGPR ~124 -> 4 waves/SIMD compatible with LDS-limited 4 blocks/CU.
__global__ void __launch_bounds__(256)
k_conv5_mfma(const unsigned short* __restrict__ x4, const unsigned short* __restrict__ wB,
             float* __restrict__ out, const float* __restrict__ bias,
             const float* __restrict__ s, const float* __restrict__ h) {
  __shared__ short8 sA[2][1280];   // 2 x 20KB halves (4 rows x 40 vox x 128B)
  const int tid  = threadIdx.x;
  const int lane = tid & 63;
  const int wid  = tid >> 6;
  const int ll   = lane & 15;
  const int l16  = lane >> 4;

  const int blk = xcd_swz(blockIdx.x, gridDim.x);
  const int xt  = blk & 1;
  const int yt  = (blk >> 1) & 15;
  const int rzb = blk >> 5;
  const int z   = rzb % D5;
  const int b   = rzb / D5;
  const int y0  = yt * 4;
  const int xbase = xt * 32;

  // per-it stage src sub-offsets within a row: chunk g = it*64 + lane (320 = 40 vox)
  int st_off[5];
  #pragma unroll
  for (int it = 0; it < 5; ++it) {
    int g = it*64 + lane;
    int v = g >> 3, c16p = g & 7;
    int c16l = c16p ^ (v & 7);
    st_off[it] = xt*4096 + (v << 7) + (c16l << 4);
  }

  const char* x4b = (const char*)x4;

  f32x4 acc[2][4];
  #pragma unroll
  for (int a = 0; a < 2; a++)
    #pragma unroll
    for (int cb = 0; cb < 4; cb++)
      acc[a][cb] = f32x4{0.f, 0.f, 0.f, 0.f};

  auto STAGE = [&](int kzn, int kyn, int hn) {
    int yin = y0 + wid + kyn; yin = yin > 62 ? 62 : yin;
    size_t rb = ((size_t)((b*D4 + z + kzn)*D4 + yin)) * 8064;
    char* dst = (char*)&sA[hn][0] + wid*5120;
    #pragma unroll
    for (int it = 0; it < 5; ++it) {
      __builtin_amdgcn_global_load_lds(
        (const __attribute__((address_space(1))) void*)(x4b + rb + st_off[it]),
        (__attribute__((address_space(3))) void*)(dst + it*1024),
        16, 0, 0);
    }
  };
  auto LDA = [&](int hh, int kx, int kk, short8 (&A)[2]) {
    #pragma unroll
    for (int a = 0; a < 2; a++) {
      int v = a*16 + ll + kx;
      int ch = hh*1280 + wid*320 + v*8 + ((kk*4 + l16) ^ (v & 7));
      A[a] = sA[0][ch];
    }
  };

  short8 A0[2], A1[2];

  STAGE(0, 0, 0);
  __syncthreads();

  int kzn = 0, kyn = 1;
  #pragma unroll 1
  for (int p = 0; p < 9; ++p) {
    const int hh = p & 1;

    short8 W[6][4];
    {
      const unsigned short* wp = wB + (size_t)p*12288 + lane*8;
      #pragma unroll
      for (int st = 0; st < 6; ++st)
        #pragma unroll
        for (int cb = 0; cb < 4; cb++)
          W[st][cb] = *reinterpret_cast<const short8*>(wp + st*2048 + cb*512);
    }
    __builtin_amdgcn_sched_barrier(0);

    if (p < 8) {
      STAGE(kzn, kyn, hh ^ 1);
      kyn++; if (kyn == 3) { kyn = 0; kzn++; }
    }
    __builtin_amdgcn_sched_barrier(0);

    LDA(hh, 0, 0, A0);
    #pragma unroll
    for (int st = 0; st < 6; ++st) {
      const int kxn = (st+1) >> 1, kkn = (st+1) & 1;
      if (st < 5) {
        if (st & 1) LDA(hh, kxn, kkn, A0); else LDA(hh, kxn, kkn, A1);
      }
      if (st & 1) c_step2(A1, W[st], acc); else c_step2(A0, W[st], acc);
    }
    __syncthreads();
  }

  const int yout = y0 + wid;
  if (yout < D5) {
    #pragma unroll
    for (int a = 0; a < 2; a++) {
      int x = xbase + a*16 + ll;
      if (x >= D5) continue;
      size_t sp = (size_t)(z*D5 + yout)*D5 + x;
      #pragma unroll
      for (int cb = 0; cb < 4; cb++)
        #pragma unroll
        for (int r = 0; r < 4; r++) {
          int co = cb*16 + l16*4 + r;
          float o = fmaxf((acc[a][cb][r] + bias[co])*s[co] + h[co], 0.f);
          out[(size_t)(b*64 + co)*D5CUBE + sp] = o;
        }
    }
  }
}

// ---------------- launcher ----------------
extern "C" void kernel_launch(void* const* d_in, const int* in_sizes, int n_in,
                              void* d_out, int out_size, void* d_ws, size_t ws_size,
                              hipStream_t stream) {
  const float* feat  = (const float*)d_in[0];
  const int*   coors = (const int*)d_in[1];
  const float* w1 = (const float*)d_in[3];
  const float* b1 = (const float*)d_in[4];
  const float* w2 = (const float*)d_in[5];
  const float* b2 = (const float*)d_in[6];
  const float* w3 = (const float*)d_in[7];
  const float* b3 = (const float*)d_in[8];
  const float* wt = (const float*)d_in[9];
  const float* bt = (const float*)d_in[10];
  const float* w5 = (const float*)d_in[11];
  const float* b5 = (const float*)d_in[12];
  const float* s1 = (const float*)d_in[13];
  const float* h1 = (const float*)d_in[14];
  const float* s2 = (const float*)d_in[15];
  const float* h2 = (const float*)d_in[16];
  const float* s3 = (const float*)d_in[17];
  const float* h3 = (const float*)d_in[18];
  const float* s4 = (const float*)d_in[19];
  const float* h4 = (const float*)d_in[20];
  const float* s5 = (const float*)d_in[21];
  const float* h5 = (const float*)d_in[22];
  int n = in_sizes[0] / 3;

  char* wsb = (char*)d_ws;
  float*          X0  = (float*)(wsb + OB_X0);
  float*          M0  = (float*)(wsb + OB_M0);
  float*          M1P = (float*)(wsb + OB_M1P);
  unsigned short* X1  = (unsigned short*)(wsb + OB_X1);
  unsigned short* X2  = (unsigned short*)(wsb + OB_X2);
  unsigned short* X3  = (unsigned short*)(wsb + OB_X3);
  float*          MT  = (float*)(wsb + OB_MT);
  unsigned short* X4  = (unsigned short*)(wsb + OB_X4);
  unsigned short* WB2 = (unsigned short*)(wsb + OB_WB2);
  unsigned short* WB3 = (unsigned short*)(wsb + OB_WB3);
  unsigned short* WBT = (unsigned short*)(wsb + OB_WBT);
  unsigned short* WB5 = (unsigned short*)(wsb + OB_WB5);

  k_zero<<<(NVP + 255)/256, 256, 0, stream>>>(X0, M0, M1P, X1, X2, X3);

  k_repack4<<<1728, 256, 0, stream>>>(w2, w3, wt, w5, WB2, WB3, WBT, WB5);

  k_scatter<<<(n+255)/256, 256, 0, stream>>>(feat, coors, n, X0, M0);

  {
    long long threads = (long long)NV1*C;
    k_conv1<<<(int)((threads+255)/256), 256, 0, stream>>>(X0, M0, X1, M1P, w1, b1, s1, h1);
  }

  constexpr int BLK23 = BB * D1 * 8;              // 496 blocks (b, z, ytile)
  k_conv23_mfma<<<BLK23, 256, 0, stream>>>(X1, WB2, X2, M1P, b2, s2, h2);
  k_conv23_mfma<<<BLK23, 256, 0, stream>>>(X2, WB3, X3, M1P, b3, s3, h3);

  k_maskT<<<(NV4 + 255)/256, 256, 0, stream>>>(M1P, MT);

  constexpr int BLK_T = BB * D4 * 16;             // 2016 blocks (b, zo, ytile)
  k_convT_mfma<<<BLK_T, 256, 0, stream>>>(X3, WBT, X4, MT, bt, s4, h4);

  constexpr int BLK5 = BB * D5 * 16 * 2;          // 3904 blocks (b, z, ytile, xtile)
  k_conv5_mfma<<<BLK5, 256, 0, stream>>>(X4, WB5, (float*)d_out, b5, s5, h5);
}

// Round 15
// 321.198 us; speedup vs baseline: 1.1081x; 1.1081x over previous
//
#include <hip/hip_runtime.h>
#include <cstdint>

// ---------------- geometry ----------------
constexpr int BB = 2, C = 64;
constexpr int D1 = 31;          // conv1 out / conv2,3 spatial
constexpr int DP = 33;          // padded spatial for x1..x3
constexpr int D4 = 63;          // conv_transpose out spatial
constexpr int D5 = 61;          // conv5 out spatial
constexpr int D5CUBE = D5*D5*D5;   // 226981

constexpr int NV1 = BB*D1*D1*D1;   // 59582
constexpr int NVP = BB*DP*DP*DP;   // 71874
constexpr int NV4 = BB*D4*D4*D4;   // 500094
constexpr int NV5 = BB*D5*D5*D5;   // 453962

// ---------------- workspace layout (byte offsets) ----------------
constexpr size_t alup(size_t x) { return (x + 255) & ~(size_t)255; }
constexpr size_t OB_X0  = 0;                                     // [NVP][3] f32
constexpr size_t OB_M0  = alup(OB_X0  + (size_t)NVP*3*4);        // [NVP] f32
constexpr size_t OB_M1P = alup(OB_M0  + (size_t)NVP*4);          // [NVP] f32 padded mask
constexpr size_t OB_X1  = alup(OB_M1P + (size_t)NVP*4);          // [NVP][64] bf16 padded
constexpr size_t OB_X2  = alup(OB_X1  + (size_t)NVP*64*2);       // [NVP][64] bf16 padded
constexpr size_t OB_X3  = alup(OB_X2  + (size_t)NVP*64*2);       // [NVP][64] bf16 padded
constexpr size_t OB_MT  = alup(OB_X3  + (size_t)NVP*64*2);       // [NV4] f32 (fully rewritten)
constexpr size_t OB_X4  = alup(OB_MT  + (size_t)NV4*4);          // [NV4][64] bf16 (fully rewritten)
constexpr size_t OB_WB2 = alup(OB_X4  + (size_t)NV4*64*2);
constexpr size_t OB_WB3 = alup(OB_WB2 + (size_t)27*64*64*2);
constexpr size_t OB_WBT = alup(OB_WB3 + (size_t)27*64*64*2);
constexpr size_t OB_WB5 = alup(OB_WBT + (size_t)27*64*64*2);

// ---------------- types / helpers ----------------
typedef __attribute__((ext_vector_type(8))) short short8;
typedef __attribute__((ext_vector_type(4))) float f32x4;

__device__ inline unsigned short f2bf(float f) {
  unsigned int u = __float_as_uint(f);
  u = (u + 0x7FFFu + ((u >> 16) & 1u)) >> 16;   // RNE
  return (unsigned short)u;
}

template<int DD>
__device__ inline void decodev(int vox, int& b, int& z, int& y, int& x) {
  x = vox % DD; int r = vox / DD;
  y = r % DD;   r /= DD;
  z = r % DD;   b = r / DD;
}

// bijective XCD-chunked block swizzle (m204)
__device__ inline int xcd_swz(int bid, int nb) {
  int q = nb >> 3, r = nb & 7;
  int xcd = bid & 7, idx = bid >> 3;
  return (xcd < r ? xcd*(q+1) : r*(q+1) + (xcd - r)*q) + idx;
}

// ---------------- per-launch zero init ----------------
__global__ void __launch_bounds__(256)
k_zero(float* __restrict__ x0, float* __restrict__ m0, float* __restrict__ m1p,
       unsigned short* __restrict__ x1, unsigned short* __restrict__ x2,
       unsigned short* __restrict__ x3) {
  int v = blockIdx.x*256 + threadIdx.x;
  if (v >= NVP) return;
  m0[v] = 0.f; m1p[v] = 0.f;
  x0[3*v+0] = 0.f; x0[3*v+1] = 0.f; x0[3*v+2] = 0.f;
  int x = v % DP, r = v / DP;
  int y = r % DP; r /= DP;
  int z = r % DP;
  if (x==0 || x==DP-1 || y==0 || y==DP-1 || z==0 || z==DP-1) {
    ulonglong2 zz = {0ull, 0ull};
    ulonglong2* p1 = (ulonglong2*)(x1 + (size_t)v*64);
    ulonglong2* p2 = (ulonglong2*)(x2 + (size_t)v*64);
    ulonglong2* p3 = (ulonglong2*)(x3 + (size_t)v*64);
    #pragma unroll
    for (int i = 0; i < 8; i++) { p1[i] = zz; p2[i] = zz; p3[i] = zz; }
  }
}

// ---------------- scatter ----------------
__global__ void k_scatter(const float* __restrict__ feat, const int* __restrict__ coors,
                          int n, float* __restrict__ x0, float* __restrict__ m0) {
  int i = blockIdx.x*blockDim.x + threadIdx.x;
  if (i >= n) return;
  int b = coors[4*i+0], z = coors[4*i+1], y = coors[4*i+2], x = coors[4*i+3];
  int v = ((b*DP + z)*DP + y)*DP + x;
  x0[v*3+0] = feat[3*i+0];
  x0[v*3+1] = feat[3*i+1];
  x0[v*3+2] = feat[3*i+2];
  m0[v] = 1.0f;
}

// ---------------- conv1: 3 -> 64, VALID, mask+act, bf16 out ----------------
__global__ void __launch_bounds__(256)
k_conv1(const float* __restrict__ x0, const float* __restrict__ m0,
        unsigned short* __restrict__ x1, float* __restrict__ m1p,
        const float* __restrict__ w1, const float* __restrict__ b1,
        const float* __restrict__ s1, const float* __restrict__ h1) {
  long long t = (long long)blockIdx.x*blockDim.x + threadIdx.x;
  if (t >= (long long)NV1*C) return;
  int co  = (int)(t & 63);
  int vox = (int)(t >> 6);
  int b, z, y, x; decodev<D1>(vox, b, z, y, x);
  float sum = 0.f, mm = 0.f;
  #pragma unroll
  for (int kz=0; kz<3; kz++)
  #pragma unroll
  for (int ky=0; ky<3; ky++)
  #pragma unroll
  for (int kx=0; kx<3; kx++) {
    int iv = ((b*DP + z+kz)*DP + y+ky)*DP + (x+kx);
    mm += m0[iv];
    const float* px = x0 + iv*3;
    const float* pw = w1 + ((kz*3+ky)*3+kx)*3*64 + co;
    sum += px[0]*pw[0] + px[1]*pw[64] + px[2]*pw[128];
  }
  bool m = mm > 0.f;
  float o = m ? fmaxf((sum + b1[co])*s1[co] + h1[co], 0.f) : 0.f;
  size_t pOff = (size_t)(((b*DP + z+1)*DP + y+1)*DP + (x+1));
  x1[pOff*C + co] = f2bf(o);
  if (co == 0) m1p[pOff] = m ? 1.f : 0.f;
}

// ---------------- fused weight repack (4 arrays) into MFMA fragment lane order ----------------
__global__ void k_repack4(const float* __restrict__ wa, const float* __restrict__ wb,
                          const float* __restrict__ wc, const float* __restrict__ wd,
                          unsigned short* __restrict__ da, unsigned short* __restrict__ db,
                          unsigned short* __restrict__ dc, unsigned short* __restrict__ dd) {
  int which = blockIdx.x / 432;
  int i = (blockIdx.x - which*432)*256 + threadIdx.x;
  const float* w = which == 0 ? wa : which == 1 ? wb : which == 2 ? wc : wd;
  unsigned short* dst = which == 0 ? da : which == 1 ? db : which == 2 ? dc : dd;
  int co = i & 63, k = (i >> 6) & 63, t = i >> 12;
  int kk = k >> 5, q = (k >> 3) & 3, j = k & 7, cb = co >> 4, l = q*16 + (co & 15);
  dst[(size_t)((t*2+kk)*4+cb)*512 + l*8 + j] = f2bf(w[i]);
}

// ---------------- mT mask precompute ----------------
__global__ void __launch_bounds__(256)
k_maskT(const float* __restrict__ m1p, float* __restrict__ mt) {
  int vox = blockIdx.x*256 + threadIdx.x;
  if (vox >= NV4) return;
  int b, zo, yo, xo; decodev<D4>(vox, b, zo, yo, xo);
  float mm = 0.f;
  for (int kz = 0; kz < 3; kz++) {
    if ((zo + kz) & 1) continue;
    int izp = ((zo + kz - 2) >> 1) + 1;
    for (int ky = 0; ky < 3; ky++) {
      if ((yo + ky) & 1) continue;
      int iyp = ((yo + ky - 2) >> 1) + 1;
      for (int kx = 0; kx < 3; kx++) {
        if ((xo + kx) & 1) continue;
        int ixp = ((xo + kx - 2) >> 1) + 1;
        mm += m1p[((b*DP + izp)*DP + iyp)*DP + ixp];
      }
    }
  }
  mt[vox] = mm;
}

__device__ __forceinline__ void c_step2(const short8 (&A)[2], const short8 (&W)[4],
                                        f32x4 (&acc)[2][4]) {
  #pragma unroll
  for (int a = 0; a < 2; a++)
    #pragma unroll
    for (int cb = 0; cb < 4; cb++)
      acc[a][cb] = __builtin_amdgcn_mfma_f32_16x16x32_bf16(W[cb], A[a], acc[a][cb], 0, 0, 0);
}

__device__ __forceinline__ void c5_step(const short8 (&A)[4], const short8 (&W)[4],
                                        f32x4 (&acc)[4][4]) {
  #pragma unroll
  for (int a = 0; a < 4; a++)
    #pragma unroll
    for (int cb = 0; cb < 4; cb++)
      acc[a][cb] = __builtin_amdgcn_mfma_f32_16x16x32_bf16(W[cb], A[a], acc[a][cb], 0, 0, 0);
}

// ---------------- conv2/3: staged 9-phase SAME conv on padded 33^3 grid ----------------
constexpr int C23_HALF = 1280;    // 1056 real chunks + pad (5*256 dst slots)

__global__ void __launch_bounds__(256)
k_conv23_mfma(const unsigned short* __restrict__ xin, const unsigned short* __restrict__ wB,
              unsigned short* __restrict__ xout, const float* __restrict__ m1p,
              const float* __restrict__ bias, const float* __restrict__ s,
              const float* __restrict__ h) {
  __shared__ short8 sA[2*C23_HALF];
  const int tid  = threadIdx.x;
  const int lane = tid & 63;
  const int wid  = tid >> 6;
  const int ll   = lane & 15;
  const int l16  = lane >> 4;

  const int blk = xcd_swz(blockIdx.x, gridDim.x);
  const int yt  = blk & 7;                 // 8 y-tiles of 4 rows
  const int rzb = blk >> 3;
  const int z   = rzb % D1;
  const int b   = rzb / D1;
  const int y0  = yt * 4;

  int st_r[5], st_base[5];
  #pragma unroll
  for (int it = 0; it < 5; ++it) {
    int g = it*256 + tid; g = g > 1055 ? 1055 : g;   // 1056 = 4 rows * 264
    int r = g / 264, rem = g - r*264;
    int v = rem >> 3, c16p = rem & 7;
    int c16l = c16p ^ (v & 7);
    st_r[it] = r;
    st_base[it] = (v << 7) + (c16l << 4);
  }

  const char* xinb = (const char*)xin;

  f32x4 acc[2][4];
  #pragma unroll
  for (int a = 0; a < 2; a++)
    #pragma unroll
    for (int cb = 0; cb < 4; cb++)
      acc[a][cb] = f32x4{0.f, 0.f, 0.f, 0.f};

  auto STAGE = [&](int kzn, int kyn, int hn) {
    size_t pb = (size_t)((b*DP + z + kzn)*DP) * (DP*128);
    char* dst = (char*)&sA[0] + hn*(C23_HALF*16);
    #pragma unroll
    for (int it = 0; it < 5; ++it) {
      int yin = y0 + st_r[it] + kyn; yin = yin > 32 ? 32 : yin;
      __builtin_amdgcn_global_load_lds(
        (const __attribute__((address_space(1))) void*)(xinb + pb + (size_t)yin*(DP*128) + st_base[it]),
        (__attribute__((address_space(3))) void*)(dst + it*4096 + wid*1024),
        16, 0, 0);
    }
  };
  auto LDA = [&](int hh, int kx, int kk, short8 (&A)[2]) {
    #pragma unroll
    for (int a = 0; a < 2; a++) {
      int xv = a*16 + ll; xv = xv > 30 ? 30 : xv;   // x=31 duplicated, discarded
      int v  = xv + kx;
      int ch = hh*C23_HALF + wid*264 + v*8 + ((kk*4 + l16) ^ (v & 7));
      A[a] = sA[ch];
    }
  };

  short8 A0[2], A1[2];

  STAGE(0, 0, 0);
  __syncthreads();

  int kzn = 0, kyn = 1;
  #pragma unroll 1
  for (int p = 0; p < 9; ++p) {
    const int hh = p & 1;

    short8 W[6][4];
    {
      const unsigned short* wp = wB + (size_t)p*12288 + lane*8;
      #pragma unroll
      for (int st = 0; st < 6; ++st)
        #pragma unroll
        for (int cb = 0; cb < 4; cb++)
          W[st][cb] = *reinterpret_cast<const short8*>(wp + st*2048 + cb*512);
    }
    __builtin_amdgcn_sched_barrier(0);

    if (p < 8) {
      STAGE(kzn, kyn, hh ^ 1);
      kyn++; if (kyn == 3) { kyn = 0; kzn++; }
    }
    __builtin_amdgcn_sched_barrier(0);

    LDA(hh, 0, 0, A0);
    #pragma unroll
    for (int st = 0; st < 6; ++st) {
      const int kxn = (st+1) >> 1, kkn = (st+1) & 1;
      if (st < 5) {
        if (st & 1) LDA(hh, kxn, kkn, A0); else LDA(hh, kxn, kkn, A1);
      }
      if (st & 1) c_step2(A1, W[st], acc); else c_step2(A0, W[st], acc);
    }
    __syncthreads();
  }

  const int y = y0 + wid;
  if (y < D1) {
    #pragma unroll
    for (int a = 0; a < 2; a++) {
      int x = a*16 + ll;
      if (x >= D1) continue;
      size_t pOff = (size_t)(((b*DP + z+1)*DP + y+1)*DP + (x+1));
      bool m = m1p[pOff] > 0.f;
      #pragma unroll
      for (int cb = 0; cb < 4; cb++) {
        unsigned long long pack = 0;
        #pragma unroll
        for (int r = 0; r < 4; r++) {
          int co = cb*16 + l16*4 + r;
          float o = m ? fmaxf((acc[a][cb][r] + bias[co])*s[co] + h[co], 0.f) : 0.f;
          pack |= (unsigned long long)f2bf(o) << (16*r);
        }
        *reinterpret_cast<unsigned long long*>(xout + pOff*64 + cb*16 + l16*4) = pack;
      }
    }
  }
}

// ---------------- convT v2: single-shot LDS-staged parity-decomposed MFMA ----------------
constexpr int CT_CHUNKS = 1792;   // 7 iters * 256 threads; 1584 used + pad

__global__ void __launch_bounds__(256)
k_convT_mfma(const unsigned short* __restrict__ x3, const unsigned short* __restrict__ wB,
             unsigned short* __restrict__ x4, const float* __restrict__ mt,
             const float* __restrict__ bias, const float* __restrict__ s,
             const float* __restrict__ h) {
  __shared__ short8 sb[CT_CHUNKS];
  const int tid  = threadIdx.x;
  const int lane = tid & 63;
  const int wid  = tid >> 6;
  const int ii   = lane & 15;
  const int l16  = lane >> 4;

  const int blk   = xcd_swz(blockIdx.x, gridDim.x);
  const int ytile = blk & 15;
  const int rzb   = blk >> 4;
  const int zo    = rzb % D4;
  const int b     = rzb / D4;
  const int y0    = ytile * 4;

  const int izp0 = (zo + (zo & 1)) >> 1;
  const int izp1 = (zo & 1) ? izp0 : izp0 + 1;

  #pragma unroll
  for (int it = 0; it < 7; ++it) {
    int g = it*256 + tid; g = g > 1583 ? 1583 : g;
    int r6 = g / 264, rem = g - r6*264;
    int v = rem >> 3, c16p = rem & 7;
    int c16l = c16p ^ (v & 7);
    int pz  = r6 >= 3 ? 1 : 0;
    int ry  = r6 - pz*3;
    int izp = pz ? izp1 : izp0;
    int iyp = ytile*2 + ry;
    size_t srcB = ((size_t)((b*DP + izp)*DP + iyp)*DP)*128 + (size_t)(v << 7) + (c16l << 4);
    __builtin_amdgcn_global_load_lds(
      (const __attribute__((address_space(1))) void*)((const char*)x3 + srcB),
      (__attribute__((address_space(3))) void*)((char*)&sb[0] + it*4096 + wid*1024),
      16, 0, 0);
  }
  __syncthreads();

  f32x4 acc[4][4];
  #pragma unroll
  for (int a = 0; a < 4; a++)
    #pragma unroll
    for (int cb = 0; cb < 4; cb++)
      acc[a][cb] = f32x4{0.f, 0.f, 0.f, 0.f};

  const int yo = y0 + wid;
  if (yo < D4) {
    const int nPz = (zo & 1) ? 1 : 2;
    #pragma unroll 1
    for (int pz = 0; pz < 2; ++pz) {
      if (pz >= nPz) break;
      const int kz = (zo & 1) ? 1 : pz*2;
      #pragma unroll 1
      for (int kyi = 0; kyi < 2; ++kyi) {
        int ky, ry;
        if (wid & 1) { if (kyi == 1) break; ky = 1; ry = (wid + 1) >> 1; }
        else         { ky = kyi*2;          ry = (wid >> 1) + kyi; }
        const int rbase = (pz*3 + ry)*264;
        #pragma unroll
        for (int kx = 0; kx < 3; ++kx) {
          const int apar  = kx & 1;
          const int xoffE = ((kx + apar - 2) >> 1) + 1;
          const int t = (kz*3 + ky)*3 + kx;
          #pragma unroll
          for (int kk = 0; kk < 2; ++kk) {
            short8 Bv[4];
            const unsigned short* wpk = wB + (size_t)(t*2+kk)*2048 + lane*8;
            #pragma unroll
            for (int cb = 0; cb < 4; cb++)
              Bv[cb] = *reinterpret_cast<const short8*>(wpk + cb*512);
            #pragma unroll
            for (int ablk = 0; ablk < 2; ablk++) {
              const int ixp = ablk*16 + ii + xoffE;
              short8 A = sb[rbase + ixp*8 + ((kk*4 + l16) ^ (ixp & 7))];
              const int afr = apar*2 + ablk;
              #pragma unroll
              for (int cb = 0; cb < 4; cb++)
                acc[afr][cb] = __builtin_amdgcn_mfma_f32_16x16x32_bf16(A, Bv[cb], acc[afr][cb], 0, 0, 0);
            }
          }
        }
      }
    }

    float bv[4], sv[4], hv[4];
    #pragma unroll
    for (int cb = 0; cb < 4; cb++) {
      int c = cb*16 + (lane & 15);
      bv[cb] = bias[c]; sv[cb] = s[c]; hv[cb] = h[c];
    }
    const int rowBase = ((b*D4 + zo)*D4 + yo)*D4;
    #pragma unroll
    for (int a = 0; a < 4; a++) {
      const int ablk = a & 1, apar = a >> 1;
      #pragma unroll
      for (int r = 0; r < 4; r++) {
        const int row = (lane >> 4)*4 + r;
        const int xo  = 2*(ablk*16 + row) + apar;
        if (xo >= D4) continue;
        const int vox = rowBase + xo;
        const bool m = mt[vox] > 0.f;
        #pragma unroll
        for (int cb = 0; cb < 4; cb++) {
          float o = m ? fmaxf((acc[a][cb][r] + bv[cb])*sv[cb] + hv[cb], 0.f) : 0.f;
          x4[(size_t)vox*64 + cb*16 + (lane & 15)] = f2bf(o);
        }
      }
    }
  }
}

// ---------------- conv5 v10 (measured best: 133us) ----------------
__global__ void __launch_bounds__(256, 2)
k_conv5_mfma(const unsigned short* __restrict__ x4, const unsigned short* __restrict__ wB,
             float* __restrict__ out, const float* __restrict__ bias,
             const float* __restrict__ s, const float* __restrict__ h) {
  __shared__ short8 sA[2][2048];   // 2 x 32KB A halves
  const int tid  = threadIdx.x;
  const int lane = tid & 63;
  const int wid  = tid >> 6;
  const int ll   = lane & 15;
  const int l16  = lane >> 4;

  const int blk   = xcd_swz(blockIdx.x, gridDim.x);
  const int ytile = blk & 15;
  const int rzb   = blk >> 4;
  const int z     = rzb % D5;
  const int b     = rzb / D5;
  const int y0    = ytile * 4;

  int st_r[8], st_base[8];
  #pragma unroll
  for (int it = 0; it < 8; ++it) {
    int g = it*256 + tid; g = g > 2015 ? 2015 : g;
    int r = g / 504, rem = g - r*504;
    int v = rem >> 3, c16p = rem & 7;
    int c16l = c16p ^ (v & 7);
    st_r[it] = r;
    st_base[it] = (v << 7) + (c16l << 4);
  }

  const char* x4b = (const char*)x4;

  f32x4 acc[4][4];
  #pragma unroll
  for (int a = 0; a < 4; a++)
    #pragma unroll
    for (int cb = 0; cb < 4; cb++)
      acc[a][cb] = f32x4{0.f, 0.f, 0.f, 0.f};

  auto STAGE_A = [&](int kzn, int kyn, int hn) {
    size_t pb = (size_t)(b*D4 + z + kzn) * (D4*D4*128);
    char* dst = (char*)&sA[hn][0];
    #pragma unroll
    for (int it = 0; it < 8; ++it) {
      int yin = y0 + st_r[it] + kyn; yin = yin > 62 ? 62 : yin;
      __builtin_amdgcn_global_load_lds(
        (const __attribute__((address_space(1))) void*)(x4b + pb + (size_t)yin*8064 + st_base[it]),
        (__attribute__((address_space(3))) void*)(dst + it*4096 + wid*1024),
        16, 0, 0);
    }
  };
  auto LDA = [&](int hh, int kx, int kk, short8 (&A)[4]) {
    #pragma unroll
    for (int a = 0; a < 4; a++) {
      int v  = a*16 + ll + kx;
      int ch = wid*504 + v*8 + ((kk*4 + l16) ^ (v & 7));
      A[a] = sA[hh][ch];
    }
  };

  short8 A0[4], A1[4], A2[4];

  STAGE_A(0, 0, 0);
  __syncthreads();

#define C5_BODY(p0,p1,p2,p3,p4,p5)                                    \
  do {                                                                 \
    LDA(hh, (p0)>>1, (p0)&1, A0);                                      \
    LDA(hh, (p1)>>1, (p1)&1, A1);                                      \
    LDA(hh, (p2)>>1, (p2)&1, A2);  c5_step(A0, W[p0], acc);            \
    LDA(hh, (p3)>>1, (p3)&1, A0);  c5_step(A1, W[p1], acc);            \
    LDA(hh, (p4)>>1, (p4)&1, A1);  c5_step(A2, W[p2], acc);            \
    LDA(hh, (p5)>>1, (p5)&1, A2);  c5_step(A0, W[p3], acc);            \
    c5_step(A1, W[p4], acc);                                           \
    c5_step(A2, W[p5], acc);                                           \
  } while (0)

  int kzn = 0, kyn = 1;
  #pragma unroll 1
  for (int p = 0; p < 9; ++p) {
    const int hh = p & 1;

    short8 W[6][4];
    {
      const unsigned short* wp = wB + (size_t)p*12288 + lane*8;
      #pragma unroll
      for (int st = 0; st < 6; ++st)
        #pragma unroll
        for (int cb = 0; cb < 4; cb++)
          W[st][cb] = *reinterpret_cast<const short8*>(wp + st*2048 + cb*512);
    }
    __builtin_amdgcn_sched_barrier(0);

    if (p < 8) {
      STAGE_A(kzn, kyn, hh ^ 1);
      kyn++; if (kyn == 3) { kyn = 0; kzn++; }
    }
    __builtin_amdgcn_sched_barrier(0);

    if ((wid & 1) == 0) {
      C5_BODY(0,1,2,3,4,5);
    } else {
      C5_BODY(3,4,5,0,1,2);
    }
    __syncthreads();
  }
#undef C5_BODY

  const int yout = y0 + wid;
  if (yout < D5) {
    #pragma unroll
    for (int a = 0; a < 4; a++) {
      int x = a*16 + ll;
      if (x >= D5) continue;
      size_t sp = (size_t)(z*D5 + yout)*D5 + x;
      #pragma unroll
      for (int cb = 0; cb < 4; cb++)
        #pragma unroll
        for (int r = 0; r < 4; r++) {
          int co = cb*16 + l16*4 + r;
          float o = fmaxf((acc[a][cb][r] + bias[co])*s[co] + h[co], 0.f);
          out[(size_t)(b*64 + co)*D5CUBE + sp] = o;
        }
    }
  }
}

// ---------------- launcher ----------------
extern "C" void kernel_launch(void* const* d_in, const int* in_sizes, int n_in,
                              void* d_out, int out_size, void* d_ws, size_t ws_size,
                              hipStream_t stream) {
  const float* feat  = (const float*)d_in[0];
  const int*   coors = (const int*)d_in[1];
  const float* w1 = (const float*)d_in[3];
  const float* b1 = (const float*)d_in[4];
  const float* w2 = (const float*)d_in[5];
  const float* b2 = (const float*)d_in[6];
  const float* w3 = (const float*)d_in[7];
  const float* b3 = (const float*)d_in[8];
  const float* wt = (const float*)d_in[9];
  const float* bt = (const float*)d_in[10];
  const float* w5 = (const float*)d_in[11];
  const float* b5 = (const float*)d_in[12];
  const float* s1 = (const float*)d_in[13];
  const float* h1 = (const float*)d_in[14];
  const float* s2 = (const float*)d_in[15];
  const float* h2 = (const float*)d_in[16];
  const float* s3 = (const float*)d_in[17];
  const float* h3 = (const float*)d_in[18];
  const float* s4 = (const float*)d_in[19];
  const float* h4 = (const float*)d_in[20];
  const float* s5 = (const float*)d_in[21];
  const float* h5 = (const float*)d_in[22];
  int n = in_sizes[0] / 3;

  char* wsb = (char*)d_ws;
  float*          X0  = (float*)(wsb + OB_X0);
  float*          M0  = (float*)(wsb + OB_M0);
  float*          M1P = (float*)(wsb + OB_M1P);
  unsigned short* X1  = (unsigned short*)(wsb + OB_X1);
  unsigned short* X2  = (unsigned short*)(wsb + OB_X2);
  unsigned short* X3  = (unsigned short*)(wsb + OB_X3);
  float*          MT  = (float*)(wsb + OB_MT);
  unsigned short* X4  = (unsigned short*)(wsb + OB_X4);
  unsigned short* WB2 = (unsigned short*)(wsb + OB_WB2);
  unsigned short* WB3 = (unsigned short*)(wsb + OB_WB3);
  unsigned short* WBT = (unsigned short*)(wsb + OB_WBT);
  unsigned short* WB5 = (unsigned short*)(wsb + OB_WB5);

  k_zero<<<(NVP + 255)/256, 256, 0, stream>>>(X0, M0, M1P, X1, X2, X3);

  k_repack4<<<1728, 256, 0, stream>>>(w2, w3, wt, w5, WB2, WB3, WBT, WB5);

  k_scatter<<<(n+255)/256, 256, 0, stream>>>(feat, coors, n, X0, M0);

  {
    long long threads = (long long)NV1*C;
    k_conv1<<<(int)((threads+255)/256), 256, 0, stream>>>(X0, M0, X1, M1P, w1, b1, s1, h1);
  }

  constexpr int BLK23 = BB * D1 * 8;              // 496 blocks (b, z, ytile)
  k_conv23_mfma<<<BLK23, 256, 0, stream>>>(X1, WB2, X2, M1P, b2, s2, h2);
  k_conv23_mfma<<<BLK23, 256, 0, stream>>>(X2, WB3, X3, M1P, b3, s3, h3);

  k_maskT<<<(NV4 + 255)/256, 256, 0, stream>>>(M1P, MT);

  constexpr int BLK_T = BB * D4 * 16;             // 2016 blocks (b, zo, ytile)
  k_convT_mfma<<<BLK_T, 256, 0, stream>>>(X3, WBT, X4, MT, bt, s4, h4);

  constexpr int BLK5 = BB * D5 * 16;              // 1952 blocks (b, z, ytile)
  k_conv5_mfma<<<BLK5, 256, 0, stream>>>(X4, WB5, (float*)d_out, b5, s5, h5);
}

// Round 16
// 319.945 us; speedup vs baseline: 1.1124x; 1.0039x over previous
//
#include <hip/hip_runtime.h>
#include <cstdint>

// ---------------- geometry ----------------
constexpr int BB = 2, C = 64;
constexpr int D1 = 31;          // conv1 out / conv2,3 spatial
constexpr int DP = 33;          // padded spatial for x1..x3
constexpr int D4 = 63;          // conv_transpose out spatial
constexpr int D5 = 61;          // conv5 out spatial
constexpr int D5CUBE = D5*D5*D5;   // 226981

constexpr int NV1 = BB*D1*D1*D1;   // 59582
constexpr int NVP = BB*DP*DP*DP;   // 71874
constexpr int NV4 = BB*D4*D4*D4;   // 500094
constexpr int NV5 = BB*D5*D5*D5;   // 453962

// ---------------- workspace layout (byte offsets) ----------------
constexpr size_t alup(size_t x) { return (x + 255) & ~(size_t)255; }
constexpr size_t OB_X0  = 0;                                     // [NVP][3] f32
constexpr size_t OB_M0  = alup(OB_X0  + (size_t)NVP*3*4);        // [NVP] f32
constexpr size_t OB_M1P = alup(OB_M0  + (size_t)NVP*4);          // [NVP] f32 padded mask
constexpr size_t OB_X1  = alup(OB_M1P + (size_t)NVP*4);          // [NVP][64] bf16 padded
constexpr size_t OB_X2  = alup(OB_X1  + (size_t)NVP*64*2);       // [NVP][64] bf16 padded
constexpr size_t OB_X3  = alup(OB_X2  + (size_t)NVP*64*2);       // [NVP][64] bf16 padded
constexpr size_t OB_MT  = alup(OB_X3  + (size_t)NVP*64*2);       // [NV4] f32 (fully rewritten)
constexpr size_t OB_X4  = alup(OB_MT  + (size_t)NV4*4);          // [NV4][64] bf16 (fully rewritten)
constexpr size_t OB_WB2 = alup(OB_X4  + (size_t)NV4*64*2);
constexpr size_t OB_WB3 = alup(OB_WB2 + (size_t)27*64*64*2);
constexpr size_t OB_WBT = alup(OB_WB3 + (size_t)27*64*64*2);
constexpr size_t OB_WB5 = alup(OB_WBT + (size_t)27*64*64*2);

// ---------------- types / helpers ----------------
typedef __attribute__((ext_vector_type(8))) short short8;
typedef __attribute__((ext_vector_type(4))) float f32x4;

__device__ inline unsigned short f2bf(float f) {
  unsigned int u = __float_as_uint(f);
  u = (u + 0x7FFFu + ((u >> 16) & 1u)) >> 16;   // RNE
  return (unsigned short)u;
}

template<int DD>
__device__ inline void decodev(int vox, int& b, int& z, int& y, int& x) {
  x = vox % DD; int r = vox / DD;
  y = r % DD;   r /= DD;
  z = r % DD;   b = r / DD;
}

// bijective XCD-chunked block swizzle (m204)
__device__ inline int xcd_swz(int bid, int nb) {
  int q = nb >> 3, r = nb & 7;
  int xcd = bid & 7, idx = bid >> 3;
  return (xcd < r ? xcd*(q+1) : r*(q+1) + (xcd - r)*q) + idx;
}

// ---------------- per-launch zero init ----------------
__global__ void __launch_bounds__(256)
k_zero(float* __restrict__ x0, float* __restrict__ m0, float* __restrict__ m1p,
       unsigned short* __restrict__ x1, unsigned short* __restrict__ x2,
       unsigned short* __restrict__ x3) {
  int v = blockIdx.x*256 + threadIdx.x;
  if (v >= NVP) return;
  m0[v] = 0.f; m1p[v] = 0.f;
  x0[3*v+0] = 0.f; x0[3*v+1] = 0.f; x0[3*v+2] = 0.f;
  int x = v % DP, r = v / DP;
  int y = r % DP; r /= DP;
  int z = r % DP;
  if (x==0 || x==DP-1 || y==0 || y==DP-1 || z==0 || z==DP-1) {
    ulonglong2 zz = {0ull, 0ull};
    ulonglong2* p1 = (ulonglong2*)(x1 + (size_t)v*64);
    ulonglong2* p2 = (ulonglong2*)(x2 + (size_t)v*64);
    ulonglong2* p3 = (ulonglong2*)(x3 + (size_t)v*64);
    #pragma unroll
    for (int i = 0; i < 8; i++) { p1[i] = zz; p2[i] = zz; p3[i] = zz; }
  }
}

// ---------------- scatter ----------------
__global__ void k_scatter(const float* __restrict__ feat, const int* __restrict__ coors,
                          int n, float* __restrict__ x0, float* __restrict__ m0) {
  int i = blockIdx.x*blockDim.x + threadIdx.x;
  if (i >= n) return;
  int b = coors[4*i+0], z = coors[4*i+1], y = coors[4*i+2], x = coors[4*i+3];
  int v = ((b*DP + z)*DP + y)*DP + x;
  x0[v*3+0] = feat[3*i+0];
  x0[v*3+1] = feat[3*i+1];
  x0[v*3+2] = feat[3*i+2];
  m0[v] = 1.0f;
}

// ---------------- conv1: 3 -> 64, VALID, mask+act, bf16 out ----------------
__global__ void __launch_bounds__(256)
k_conv1(const float* __restrict__ x0, const float* __restrict__ m0,
        unsigned short* __restrict__ x1, float* __restrict__ m1p,
        const float* __restrict__ w1, const float* __restrict__ b1,
        const float* __restrict__ s1, const float* __restrict__ h1) {
  long long t = (long long)blockIdx.x*blockDim.x + threadIdx.x;
  if (t >= (long long)NV1*C) return;
  int co  = (int)(t & 63);
  int vox = (int)(t >> 6);
  int b, z, y, x; decodev<D1>(vox, b, z, y, x);
  float sum = 0.f, mm = 0.f;
  #pragma unroll
  for (int kz=0; kz<3; kz++)
  #pragma unroll
  for (int ky=0; ky<3; ky++)
  #pragma unroll
  for (int kx=0; kx<3; kx++) {
    int iv = ((b*DP + z+kz)*DP + y+ky)*DP + (x+kx);
    mm += m0[iv];
    const float* px = x0 + iv*3;
    const float* pw = w1 + ((kz*3+ky)*3+kx)*3*64 + co;
    sum += px[0]*pw[0] + px[1]*pw[64] + px[2]*pw[128];
  }
  bool m = mm > 0.f;
  float o = m ? fmaxf((sum + b1[co])*s1[co] + h1[co], 0.f) : 0.f;
  size_t pOff = (size_t)(((b*DP + z+1)*DP + y+1)*DP + (x+1));
  x1[pOff*C + co] = f2bf(o);
  if (co == 0) m1p[pOff] = m ? 1.f : 0.f;
}

// ---------------- fused weight repack (4 arrays) into MFMA fragment lane order ----------------
__global__ void k_repack4(const float* __restrict__ wa, const float* __restrict__ wb,
                          const float* __restrict__ wc, const float* __restrict__ wd,
                          unsigned short* __restrict__ da, unsigned short* __restrict__ db,
                          unsigned short* __restrict__ dc, unsigned short* __restrict__ dd) {
  int which = blockIdx.x / 432;
  int i = (blockIdx.x - which*432)*256 + threadIdx.x;
  const float* w = which == 0 ? wa : which == 1 ? wb : which == 2 ? wc : wd;
  unsigned short* dst = which == 0 ? da : which == 1 ? db : which == 2 ? dc : dd;
  int co = i & 63, k = (i >> 6) & 63, t = i >> 12;
  int kk = k >> 5, q = (k >> 3) & 3, j = k & 7, cb = co >> 4, l = q*16 + (co & 15);
  dst[(size_t)((t*2+kk)*4+cb)*512 + l*8 + j] = f2bf(w[i]);
}

// ---------------- mT mask precompute ----------------
__global__ void __launch_bounds__(256)
k_maskT(const float* __restrict__ m1p, float* __restrict__ mt) {
  int vox = blockIdx.x*256 + threadIdx.x;
  if (vox >= NV4) return;
  int b, zo, yo, xo; decodev<D4>(vox, b, zo, yo, xo);
  float mm = 0.f;
  for (int kz = 0; kz < 3; kz++) {
    if ((zo + kz) & 1) continue;
    int izp = ((zo + kz - 2) >> 1) + 1;
    for (int ky = 0; ky < 3; ky++) {
      if ((yo + ky) & 1) continue;
      int iyp = ((yo + ky - 2) >> 1) + 1;
      for (int kx = 0; kx < 3; kx++) {
        if ((xo + kx) & 1) continue;
        int ixp = ((xo + kx - 2) >> 1) + 1;
        mm += m1p[((b*DP + izp)*DP + iyp)*DP + ixp];
      }
    }
  }
  mt[vox] = mm;
}

__device__ __forceinline__ void c_step2(const short8 (&A)[2], const short8 (&W)[4],
                                        f32x4 (&acc)[2][4]) {
  #pragma unroll
  for (int a = 0; a < 2; a++)
    #pragma unroll
    for (int cb = 0; cb < 4; cb++)
      acc[a][cb] = __builtin_amdgcn_mfma_f32_16x16x32_bf16(W[cb], A[a], acc[a][cb], 0, 0, 0);
}

__device__ __forceinline__ void c5_step(const short8 (&A)[4], const short8 (&W)[4],
                                        f32x4 (&acc)[4][4]) {
  #pragma unroll
  for (int a = 0; a < 4; a++)
    #pragma unroll
    for (int cb = 0; cb < 4; cb++)
      acc[a][cb] = __builtin_amdgcn_mfma_f32_16x16x32_bf16(W[cb], A[a], acc[a][cb], 0, 0, 0);
}

// ---------------- conv2/3: staged 9-phase SAME conv on padded 33^3 grid ----------------
constexpr int C23_HALF = 1280;    // 1056 real chunks + pad (5*256 dst slots)

__global__ void __launch_bounds__(256)
k_conv23_mfma(const unsigned short* __restrict__ xin, const unsigned short* __restrict__ wB,
              unsigned short* __restrict__ xout, const float* __restrict__ m1p,
              const float* __restrict__ bias, const float* __restrict__ s,
              const float* __restrict__ h) {
  __shared__ short8 sA[2*C23_HALF];
  const int tid  = threadIdx.x;
  const int lane = tid & 63;
  const int wid  = tid >> 6;
  const int ll   = lane & 15;
  const int l16  = lane >> 4;

  const int blk = xcd_swz(blockIdx.x, gridDim.x);
  const int yt  = blk & 7;                 // 8 y-tiles of 4 rows
  const int rzb = blk >> 3;
  const int z   = rzb % D1;
  const int b   = rzb / D1;
  const int y0  = yt * 4;

  int st_r[5], st_base[5];
  #pragma unroll
  for (int it = 0; it < 5; ++it) {
    int g = it*256 + tid; g = g > 1055 ? 1055 : g;   // 1056 = 4 rows * 264
    int r = g / 264, rem = g - r*264;
    int v = rem >> 3, c16p = rem & 7;
    int c16l = c16p ^ (v & 7);
    st_r[it] = r;
    st_base[it] = (v << 7) + (c16l << 4);
  }

  const char* xinb = (const char*)xin;

  f32x4 acc[2][4];
  #pragma unroll
  for (int a = 0; a < 2; a++)
    #pragma unroll
    for (int cb = 0; cb < 4; cb++)
      acc[a][cb] = f32x4{0.f, 0.f, 0.f, 0.f};

  auto STAGE = [&](int kzn, int kyn, int hn) {
    size_t pb = (size_t)((b*DP + z + kzn)*DP) * (DP*128);
    char* dst = (char*)&sA[0] + hn*(C23_HALF*16);
    #pragma unroll
    for (int it = 0; it < 5; ++it) {
      int yin = y0 + st_r[it] + kyn; yin = yin > 32 ? 32 : yin;
      __builtin_amdgcn_global_load_lds(
        (const __attribute__((address_space(1))) void*)(xinb + pb + (size_t)yin*(DP*128) + st_base[it]),
        (__attribute__((address_space(3))) void*)(dst + it*4096 + wid*1024),
        16, 0, 0);
    }
  };
  auto LDA = [&](int hh, int kx, int kk, short8 (&A)[2]) {
    #pragma unroll
    for (int a = 0; a < 2; a++) {
      int xv = a*16 + ll; xv = xv > 30 ? 30 : xv;   // x=31 duplicated, discarded
      int v  = xv + kx;
      int ch = hh*C23_HALF + wid*264 + v*8 + ((kk*4 + l16) ^ (v & 7));
      A[a] = sA[ch];
    }
  };

  short8 A0[2], A1[2];

  STAGE(0, 0, 0);
  __syncthreads();

  int kzn = 0, kyn = 1;
  #pragma unroll 1
  for (int p = 0; p < 9; ++p) {
    const int hh = p & 1;

    short8 W[6][4];
    {
      const unsigned short* wp = wB + (size_t)p*12288 + lane*8;
      #pragma unroll
      for (int st = 0; st < 6; ++st)
        #pragma unroll
        for (int cb = 0; cb < 4; cb++)
          W[st][cb] = *reinterpret_cast<const short8*>(wp + st*2048 + cb*512);
    }
    __builtin_amdgcn_sched_barrier(0);

    if (p < 8) {
      STAGE(kzn, kyn, hh ^ 1);
      kyn++; if (kyn == 3) { kyn = 0; kzn++; }
    }
    __builtin_amdgcn_sched_barrier(0);

    LDA(hh, 0, 0, A0);
    #pragma unroll
    for (int st = 0; st < 6; ++st) {
      const int kxn = (st+1) >> 1, kkn = (st+1) & 1;
      if (st < 5) {
        if (st & 1) LDA(hh, kxn, kkn, A0); else LDA(hh, kxn, kkn, A1);
      }
      if (st & 1) c_step2(A1, W[st], acc); else c_step2(A0, W[st], acc);
    }
    __syncthreads();
  }

  const int y = y0 + wid;
  if (y < D1) {
    #pragma unroll
    for (int a = 0; a < 2; a++) {
      int x = a*16 + ll;
      if (x >= D1) continue;
      size_t pOff = (size_t)(((b*DP + z+1)*DP + y+1)*DP + (x+1));
      bool m = m1p[pOff] > 0.f;
      #pragma unroll
      for (int cb = 0; cb < 4; cb++) {
        unsigned long long pack = 0;
        #pragma unroll
        for (int r = 0; r < 4; r++) {
          int co = cb*16 + l16*4 + r;
          float o = m ? fmaxf((acc[a][cb][r] + bias[co])*s[co] + h[co], 0.f) : 0.f;
          pack |= (unsigned long long)f2bf(o) << (16*r);
        }
        *reinterpret_cast<unsigned long long*>(xout + pOff*64 + cb*16 + l16*4) = pack;
      }
    }
  }
}

// ---------------- convT v2: single-shot LDS-staged parity-decomposed MFMA ----------------
constexpr int CT_CHUNKS = 1792;   // 7 iters * 256 threads; 1584 used + pad

__global__ void __launch_bounds__(256)
k_convT_mfma(const unsigned short* __restrict__ x3, const unsigned short* __restrict__ wB,
             unsigned short* __restrict__ x4, const float* __restrict__ mt,
             const float* __restrict__ bias, const float* __restrict__ s,
             const float* __restrict__ h) {
  __shared__ short8 sb[CT_CHUNKS];
  const int tid  = threadIdx.x;
  const int lane = tid & 63;
  const int wid  = tid >> 6;
  const int ii   = lane & 15;
  const int l16  = lane >> 4;

  const int blk   = xcd_swz(blockIdx.x, gridDim.x);
  const int ytile = blk & 15;
  const int rzb   = blk >> 4;
  const int zo    = rzb % D4;
  const int b     = rzb / D4;
  const int y0    = ytile * 4;

  const int izp0 = (zo + (zo & 1)) >> 1;
  const int izp1 = (zo & 1) ? izp0 : izp0 + 1;

  #pragma unroll
  for (int it = 0; it < 7; ++it) {
    int g = it*256 + tid; g = g > 1583 ? 1583 : g;
    int r6 = g / 264, rem = g - r6*264;
    int v = rem >> 3, c16p = rem & 7;
    int c16l = c16p ^ (v & 7);
    int pz  = r6 >= 3 ? 1 : 0;
    int ry  = r6 - pz*3;
    int izp = pz ? izp1 : izp0;
    int iyp = ytile*2 + ry;
    size_t srcB = ((size_t)((b*DP + izp)*DP + iyp)*DP)*128 + (size_t)(v << 7) + (c16l << 4);
    __builtin_amdgcn_global_load_lds(
      (const __attribute__((address_space(1))) void*)((const char*)x3 + srcB),
      (__attribute__((address_space(3))) void*)((char*)&sb[0] + it*4096 + wid*1024),
      16, 0, 0);
  }
  __syncthreads();

  f32x4 acc[4][4];
  #pragma unroll
  for (int a = 0; a < 4; a++)
    #pragma unroll
    for (int cb = 0; cb < 4; cb++)
      acc[a][cb] = f32x4{0.f, 0.f, 0.f, 0.f};

  const int yo = y0 + wid;
  if (yo < D4) {
    const int nPz = (zo & 1) ? 1 : 2;
    #pragma unroll 1
    for (int pz = 0; pz < 2; ++pz) {
      if (pz >= nPz) break;
      const int kz = (zo & 1) ? 1 : pz*2;
      #pragma unroll 1
      for (int kyi = 0; kyi < 2; ++kyi) {
        int ky, ry;
        if (wid & 1) { if (kyi == 1) break; ky = 1; ry = (wid + 1) >> 1; }
        else         { ky = kyi*2;          ry = (wid >> 1) + kyi; }
        const int rbase = (pz*3 + ry)*264;
        #pragma unroll
        for (int kx = 0; kx < 3; ++kx) {
          const int apar  = kx & 1;
          const int xoffE = ((kx + apar - 2) >> 1) + 1;
          const int t = (kz*3 + ky)*3 + kx;
          #pragma unroll
          for (int kk = 0; kk < 2; ++kk) {
            short8 Bv[4];
            const unsigned short* wpk = wB + (size_t)(t*2+kk)*2048 + lane*8;
            #pragma unroll
            for (int cb = 0; cb < 4; cb++)
              Bv[cb] = *reinterpret_cast<const short8*>(wpk + cb*512);
            #pragma unroll
            for (int ablk = 0; ablk < 2; ablk++) {
              const int ixp = ablk*16 + ii + xoffE;
              short8 A = sb[rbase + ixp*8 + ((kk*4 + l16) ^ (ixp & 7))];
              const int afr = apar*2 + ablk;
              #pragma unroll
              for (int cb = 0; cb < 4; cb++)
                acc[afr][cb] = __builtin_amdgcn_mfma_f32_16x16x32_bf16(A, Bv[cb], acc[afr][cb], 0, 0, 0);
            }
          }
        }
      }
    }

    float bv[4], sv[4], hv[4];
    #pragma unroll
    for (int cb = 0; cb < 4; cb++) {
      int c = cb*16 + (lane & 15);
      bv[cb] = bias[c]; sv[cb] = s[c]; hv[cb] = h[c];
    }
    const int rowBase = ((b*D4 + zo)*D4 + yo)*D4;
    #pragma unroll
    for (int a = 0; a < 4; a++) {
      const int ablk = a & 1, apar = a >> 1;
      #pragma unroll
      for (int r = 0; r < 4; r++) {
        const int row = (lane >> 4)*4 + r;
        const int xo  = 2*(ablk*16 + row) + apar;
        if (xo >= D4) continue;
        const int vox = rowBase + xo;
        const bool m = mt[vox] > 0.f;
        #pragma unroll
        for (int cb = 0; cb < 4; cb++) {
          float o = m ? fmaxf((acc[a][cb][r] + bv[cb])*sv[cb] + hv[cb], 0.f) : 0.f;
          x4[(size_t)vox*64 + cb*16 + (lane & 15)] = f2bf(o);
        }
      }
    }
  }
}

// ---------------- conv5 v12: barrier-free per-wave async pipeline ----------------
// Block = 4 waves; wave wid owns out row (b, z, y0+wid), 61 x, 64 co. 9 phases
// (kz,ky). Each wave stages ITS OWN input row (y0+wid+ky of plane z+kz) into its
// private double-buffered LDS slot -> writer == reader, so NO __syncthreads at
// all. Per phase, issue order: [24 W loads][8 DMA for p+1 (always; p=8 re-stages
// a clamped row so counts stay uniform)] then s_waitcnt vmcnt(8): the 8 newest
// ops are the p+1 DMAs, so this guarantees DMA(p)+W(p) landed WITHOUT draining
// the prefetch — correct whether or not the allocator sinks the W loads.
constexpr int C5_WSLOT = 544;   // chunks per wave-half: 504 used + overflow pad

__global__ void __launch_bounds__(256, 2)
k_conv5_mfma(const unsigned short* __restrict__ x4, const unsigned short* __restrict__ wB,
             float* __restrict__ out, const float* __restrict__ bias,
             const float* __restrict__ s, const float* __restrict__ h) {
  __shared__ short8 sA[2*4*C5_WSLOT];   // 68KB
  const int tid  = threadIdx.x;
  const int lane = tid & 63;
  const int wid  = tid >> 6;
  const int ll   = lane & 15;
  const int l16  = lane >> 4;

  const int blk   = xcd_swz(blockIdx.x, gridDim.x);
  const int ytile = blk & 15;
  const int rzb   = blk >> 4;
  const int z     = rzb % D5;
  const int b     = rzb / D5;
  const int y0    = ytile * 4;

  // per-wave stage source offsets: chunk g = it*64 + lane (504 real, clamp dup)
  int st_off[8];
  #pragma unroll
  for (int it = 0; it < 8; ++it) {
    int g = it*64 + lane; g = g > 503 ? 503 : g;
    int v = g >> 3, c16p = g & 7;
    int c16l = c16p ^ (v & 7);              // logical chunk stored at phys c16p
    st_off[it] = (v << 7) + (c16l << 4);
  }

  const char* x4b = (const char*)x4;

  f32x4 acc[4][4];
  #pragma unroll
  for (int a = 0; a < 4; a++)
    #pragma unroll
    for (int cb = 0; cb < 4; cb++)
      acc[a][cb] = f32x4{0.f, 0.f, 0.f, 0.f};

  auto STAGE = [&](int kzn, int kyn, int hn) {
    int yin = y0 + wid + kyn; yin = yin > 62 ? 62 : yin;
    size_t rb = ((size_t)((b*D4 + z + kzn)*D4 + yin)) * 8064;
    char* dst = (char*)&sA[0] + (size_t)(hn*4 + wid)*(C5_WSLOT*16);
    #pragma unroll
    for (int it = 0; it < 8; ++it) {
      __builtin_amdgcn_global_load_lds(
        (const __attribute__((address_space(1))) void*)(x4b + rb + st_off[it]),
        (__attribute__((address_space(3))) void*)(dst + it*1024),
        16, 0, 0);
    }
  };
  auto LDA = [&](int hh, int kx, int kk, short8 (&A)[4]) {
    #pragma unroll
    for (int a = 0; a < 4; a++) {
      int v  = a*16 + ll + kx;
      int ch = (hh*4 + wid)*C5_WSLOT + v*8 + ((kk*4 + l16) ^ (v & 7));
      A[a] = sA[ch];
    }
  };

  short8 A0[4], A1[4], A2[4];

  // prologue: stage phase 0 into half 0 (no barrier needed — per-wave regions)
  STAGE(0, 0, 0);

#define C5_BODY(p0,p1,p2,p3,p4,p5)                                    \
  do {                                                                 \
    LDA(hh, (p0)>>1, (p0)&1, A0);                                      \
    LDA(hh, (p1)>>1, (p1)&1, A1);                                      \
    LDA(hh, (p2)>>1, (p2)&1, A2);  c5_step(A0, W[p0], acc);            \
    LDA(hh, (p3)>>1, (p3)&1, A0);  c5_step(A1, W[p1], acc);            \
    LDA(hh, (p4)>>1, (p4)&1, A1);  c5_step(A2, W[p2], acc);            \
    LDA(hh, (p5)>>1, (p5)&1, A2);  c5_step(A0, W[p3], acc);            \
    c5_step(A1, W[p4], acc);                                           \
    c5_step(A2, W[p5], acc);                                           \
  } while (0)

  int kzn = 0, kyn = 1;
  #pragma unroll 1
  for (int p = 0; p < 9; ++p) {
    const int hh = p & 1;

    // (1) W block for this phase (older than the DMAs below)
    short8 W[6][4];
    {
      const unsigned short* wp = wB + (size_t)p*12288 + lane*8;
      #pragma unroll
      for (int st = 0; st < 6; ++st)
        #pragma unroll
        for (int cb = 0; cb < 4; cb++)
          W[st][cb] = *reinterpret_cast<const short8*>(wp + st*2048 + cb*512);
    }
    __builtin_amdgcn_sched_barrier(0);

    // (2) DMA phase p+1's row (always 8 issues; p=8 re-stages clamped (2,2))
    if (p < 8) {
      STAGE(kzn, kyn, hh ^ 1);
      kyn++; if (kyn == 3) { kyn = 0; kzn++; }
    } else {
      STAGE(2, 2, hh ^ 1);                 // dummy: keeps vmcnt count uniform
    }
    __builtin_amdgcn_sched_barrier(0);

    // (3) A-readiness: 8 newest = p+1 DMAs; all older (DMA p, W p) are done.
    asm volatile("s_waitcnt vmcnt(8)" ::: "memory");
    __builtin_amdgcn_sched_barrier(0);

    // (4) compute — no block barrier anywhere
    C5_BODY(0,1,2,3,4,5);
  }
#undef C5_BODY

  const int yout = y0 + wid;
  if (yout < D5) {
    #pragma unroll
    for (int a = 0; a < 4; a++) {
      int x = a*16 + ll;
      if (x >= D5) continue;
      size_t sp = (size_t)(z*D5 + yout)*D5 + x;
      #pragma unroll
      for (int cb = 0; cb < 4; cb++)
        #pragma unroll
        for (int r = 0; r < 4; r++) {
          int co = cb*16 + l16*4 + r;
          float o = fmaxf((acc[a][cb][r] + bias[co])*s[co] + h[co], 0.f);
          out[(size_t)(b*64 + co)*D5CUBE + sp] = o;
        }
    }
  }
}

// ---------------- launcher ----------------
extern "C" void kernel_launch(void* const* d_in, const int* in_sizes, int n_in,
                              void* d_out, int out_size, void* d_ws, size_t ws_size,
                              hipStream_t stream) {
  const float* feat  = (const float*)d_in[0];
  const int*   coors = (const int*)d_in[1];
  const float* w1 = (const float*)d_in[3];
  const float* b1 = (const float*)d_in[4];
  const float* w2 = (const float*)d_in[5];
  const float* b2 = (const float*)d_in[6];
  const float* w3 = (const float*)d_in[7];
  const float* b3 = (const float*)d_in[8];
  const float* wt = (const float*)d_in[9];
  const float* bt = (const float*)d_in[10];
  const float* w5 = (const float*)d_in[11];
  const float* b5 = (const float*)d_in[12];
  const float* s1 = (const float*)d_in[13];
  const float* h1 = (const float*)d_in[14];
  const float* s2 = (const float*)d_in[15];
  const float* h2 = (const float*)d_in[16];
  const float* s3 = (const float*)d_in[17];
  const float* h3 = (const float*)d_in[18];
  const float* s4 = (const float*)d_in[19];
  const float* h4 = (const float*)d_in[20];
  const float* s5 = (const float*)d_in[21];
  const float* h5 = (const float*)d_in[22];
  int n = in_sizes[0] / 3;

  char* wsb = (char*)d_ws;
  float*          X0  = (float*)(wsb + OB_X0);
  float*          M0  = (float*)(wsb + OB_M0);
  float*          M1P = (float*)(wsb + OB_M1P);
  unsigned short* X1  = (unsigned short*)(wsb + OB_X1);
  unsigned short* X2  = (unsigned short*)(wsb + OB_X2);
  unsigned short* X3  = (unsigned short*)(wsb + OB_X3);
  float*          MT  = (float*)(wsb + OB_MT);
  unsigned short* X4  = (unsigned short*)(wsb + OB_X4);
  unsigned short* WB2 = (unsigned short*)(wsb + OB_WB2);
  unsigned short* WB3 = (unsigned short*)(wsb + OB_WB3);
  unsigned short* WBT = (unsigned short*)(wsb + OB_WBT);
  unsigned short* WB5 = (unsigned short*)(wsb + OB_WB5);

  k_zero<<<(NVP + 255)/256, 256, 0, stream>>>(X0, M0, M1P, X1, X2, X3);

  k_repack4<<<1728, 256, 0, stream>>>(w2, w3, wt, w5, WB2, WB3, WBT, WB5);

  k_scatter<<<(n+255)/256, 256, 0, stream>>>(feat, coors, n, X0, M0);

  {
    long long threads = (long long)NV1*C;
    k_conv1<<<(int)((threads+255)/256), 256, 0, stream>>>(X0, M0, X1, M1P, w1, b1, s1, h1);
  }

  constexpr int BLK23 = BB * D1 * 8;              // 496 blocks (b, z, ytile)
  k_conv23_mfma<<<BLK23, 256, 0, stream>>>(X1, WB2, X2, M1P, b2, s2, h2);
  k_conv23_mfma<<<BLK23, 256, 0, stream>>>(X2, WB3, X3, M1P, b3, s3, h3);

  k_maskT<<<(NV4 + 255)/256, 256, 0, stream>>>(M1P, MT);

  constexpr int BLK_T = BB * D4 * 16;             // 2016 blocks (b, zo, ytile)
  k_convT_mfma<<<BLK_T, 256, 0, stream>>>(X3, WBT, X4, MT, bt, s4, h4);

  constexpr int BLK5 = BB * D5 * 16;              // 1952 blocks (b, z, ytile)
  k_conv5_mfma<<<BLK5, 256, 0, stream>>>(X4, WB5, (float*)d_out, b5, s5, h5);
}

// Round 17
// 310.670 us; speedup vs baseline: 1.1456x; 1.0299x over previous
//
#include <hip/hip_runtime.h>
#include <cstdint>

// ---------------- geometry ----------------
constexpr int BB = 2, C = 64;
constexpr int D1 = 31;          // conv1 out / conv2,3 spatial
constexpr int DP = 33;          // padded spatial for x1..x3
constexpr int D4 = 63;          // conv_transpose out spatial
constexpr int D5 = 61;          // conv5 out spatial
constexpr int D5CUBE = D5*D5*D5;   // 226981

constexpr int NV1 = BB*D1*D1*D1;   // 59582
constexpr int NVP = BB*DP*DP*DP;   // 71874
constexpr int NV4 = BB*D4*D4*D4;   // 500094
constexpr int NV5 = BB*D5*D5*D5;   // 453962

// ---------------- workspace layout (byte offsets) ----------------
constexpr size_t alup(size_t x) { return (x + 255) & ~(size_t)255; }
constexpr size_t OB_X0  = 0;                                     // [NVP][3] f32
constexpr size_t OB_M0  = alup(OB_X0  + (size_t)NVP*3*4);        // [NVP] f32
constexpr size_t OB_M1P = alup(OB_M0  + (size_t)NVP*4);          // [NVP] f32 padded mask
constexpr size_t OB_X1  = alup(OB_M1P + (size_t)NVP*4);          // [NVP][64] bf16 padded
constexpr size_t OB_X2  = alup(OB_X1  + (size_t)NVP*64*2);       // [NVP][64] bf16 padded
constexpr size_t OB_X3  = alup(OB_X2  + (size_t)NVP*64*2);       // [NVP][64] bf16 padded
constexpr size_t OB_X4  = alup(OB_X3  + (size_t)NVP*64*2);       // [NV4][64] bf16 (fully rewritten)
constexpr size_t OB_WB2 = alup(OB_X4  + (size_t)NV4*64*2);
constexpr size_t OB_WB3 = alup(OB_WB2 + (size_t)27*64*64*2);
constexpr size_t OB_WBT = alup(OB_WB3 + (size_t)27*64*64*2);
constexpr size_t OB_WB5 = alup(OB_WBT + (size_t)27*64*64*2);

// ---------------- types / helpers ----------------
typedef __attribute__((ext_vector_type(8))) short short8;
typedef __attribute__((ext_vector_type(4))) float f32x4;

__device__ inline unsigned short f2bf(float f) {
  unsigned int u = __float_as_uint(f);
  u = (u + 0x7FFFu + ((u >> 16) & 1u)) >> 16;   // RNE
  return (unsigned short)u;
}

template<int DD>
__device__ inline void decodev(int vox, int& b, int& z, int& y, int& x) {
  x = vox % DD; int r = vox / DD;
  y = r % DD;   r /= DD;
  z = r % DD;   b = r / DD;
}

// bijective XCD-chunked block swizzle (m204)
__device__ inline int xcd_swz(int bid, int nb) {
  int q = nb >> 3, r = nb & 7;
  int xcd = bid & 7, idx = bid >> 3;
  return (xcd < r ? xcd*(q+1) : r*(q+1) + (xcd - r)*q) + idx;
}

// ---------------- fused setup: zero-init (blocks 0..280) + weight repack (281..2008) ----------------
constexpr int SETUP_ZBLK = (NVP + 255) / 256;   // 281

__global__ void __launch_bounds__(256)
k_setup(float* __restrict__ x0, float* __restrict__ m0, float* __restrict__ m1p,
        unsigned short* __restrict__ x1, unsigned short* __restrict__ x2,
        unsigned short* __restrict__ x3,
        const float* __restrict__ wa, const float* __restrict__ wb,
        const float* __restrict__ wc, const float* __restrict__ wd,
        unsigned short* __restrict__ da, unsigned short* __restrict__ db,
        unsigned short* __restrict__ dc, unsigned short* __restrict__ dd) {
  if (blockIdx.x < SETUP_ZBLK) {
    int v = blockIdx.x*256 + threadIdx.x;
    if (v >= NVP) return;
    m0[v] = 0.f; m1p[v] = 0.f;
    x0[3*v+0] = 0.f; x0[3*v+1] = 0.f; x0[3*v+2] = 0.f;
    int x = v % DP, r = v / DP;
    int y = r % DP; r /= DP;
    int z = r % DP;
    if (x==0 || x==DP-1 || y==0 || y==DP-1 || z==0 || z==DP-1) {
      ulonglong2 zz = {0ull, 0ull};
      ulonglong2* p1 = (ulonglong2*)(x1 + (size_t)v*64);
      ulonglong2* p2 = (ulonglong2*)(x2 + (size_t)v*64);
      ulonglong2* p3 = (ulonglong2*)(x3 + (size_t)v*64);
      #pragma unroll
      for (int i = 0; i < 8; i++) { p1[i] = zz; p2[i] = zz; p3[i] = zz; }
    }
  } else {
    int rblk = blockIdx.x - SETUP_ZBLK;
    int which = rblk / 432;
    int i = (rblk - which*432)*256 + threadIdx.x;
    const float* w = which == 0 ? wa : which == 1 ? wb : which == 2 ? wc : wd;
    unsigned short* dst = which == 0 ? da : which == 1 ? db : which == 2 ? dc : dd;
    int co = i & 63, k = (i >> 6) & 63, t = i >> 12;
    int kk = k >> 5, q = (k >> 3) & 3, j = k & 7, cb = co >> 4, l = q*16 + (co & 15);
    dst[(size_t)((t*2+kk)*4+cb)*512 + l*8 + j] = f2bf(w[i]);
  }
}

// ---------------- scatter ----------------
__global__ void k_scatter(const float* __restrict__ feat, const int* __restrict__ coors,
                          int n, float* __restrict__ x0, float* __restrict__ m0) {
  int i = blockIdx.x*blockDim.x + threadIdx.x;
  if (i >= n) return;
  int b = coors[4*i+0], z = coors[4*i+1], y = coors[4*i+2], x = coors[4*i+3];
  int v = ((b*DP + z)*DP + y)*DP + x;
  x0[v*3+0] = feat[3*i+0];
  x0[v*3+1] = feat[3*i+1];
  x0[v*3+2] = feat[3*i+2];
  m0[v] = 1.0f;
}

// ---------------- conv1: 3 -> 64, VALID, mask+act, bf16 out ----------------
__global__ void __launch_bounds__(256)
k_conv1(const float* __restrict__ x0, const float* __restrict__ m0,
        unsigned short* __restrict__ x1, float* __restrict__ m1p,
        const float* __restrict__ w1, const float* __restrict__ b1,
        const float* __restrict__ s1, const float* __restrict__ h1) {
  long long t = (long long)blockIdx.x*blockDim.x + threadIdx.x;
  if (t >= (long long)NV1*C) return;
  int co  = (int)(t & 63);
  int vox = (int)(t >> 6);
  int b, z, y, x; decodev<D1>(vox, b, z, y, x);
  float sum = 0.f, mm = 0.f;
  #pragma unroll
  for (int kz=0; kz<3; kz++)
  #pragma unroll
  for (int ky=0; ky<3; ky++)
  #pragma unroll
  for (int kx=0; kx<3; kx++) {
    int iv = ((b*DP + z+kz)*DP + y+ky)*DP + (x+kx);
    mm += m0[iv];
    const float* px = x0 + iv*3;
    const float* pw = w1 + ((kz*3+ky)*3+kx)*3*64 + co;
    sum += px[0]*pw[0] + px[1]*pw[64] + px[2]*pw[128];
  }
  bool m = mm > 0.f;
  float o = m ? fmaxf((sum + b1[co])*s1[co] + h1[co], 0.f) : 0.f;
  size_t pOff = (size_t)(((b*DP + z+1)*DP + y+1)*DP + (x+1));
  x1[pOff*C + co] = f2bf(o);
  if (co == 0) m1p[pOff] = m ? 1.f : 0.f;
}

__device__ __forceinline__ void c_step2(const short8 (&A)[2], const short8 (&W)[4],
                                        f32x4 (&acc)[2][4]) {
  #pragma unroll
  for (int a = 0; a < 2; a++)
    #pragma unroll
    for (int cb = 0; cb < 4; cb++)
      acc[a][cb] = __builtin_amdgcn_mfma_f32_16x16x32_bf16(W[cb], A[a], acc[a][cb], 0, 0, 0);
}

__device__ __forceinline__ void c5_step(const short8 (&A)[4], const short8 (&W)[4],
                                        f32x4 (&acc)[4][4]) {
  #pragma unroll
  for (int a = 0; a < 4; a++)
    #pragma unroll
    for (int cb = 0; cb < 4; cb++)
      acc[a][cb] = __builtin_amdgcn_mfma_f32_16x16x32_bf16(W[cb], A[a], acc[a][cb], 0, 0, 0);
}

// ---------------- conv2/3: staged 9-phase SAME conv on padded 33^3 grid ----------------
constexpr int C23_HALF = 1280;    // 1056 real chunks + pad (5*256 dst slots)

__global__ void __launch_bounds__(256)
k_conv23_mfma(const unsigned short* __restrict__ xin, const unsigned short* __restrict__ wB,
              unsigned short* __restrict__ xout, const float* __restrict__ m1p,
              const float* __restrict__ bias, const float* __restrict__ s,
              const float* __restrict__ h) {
  __shared__ short8 sA[2*C23_HALF];
  const int tid  = threadIdx.x;
  const int lane = tid & 63;
  const int wid  = tid >> 6;
  const int ll   = lane & 15;
  const int l16  = lane >> 4;

  const int blk = xcd_swz(blockIdx.x, gridDim.x);
  const int yt  = blk & 7;                 // 8 y-tiles of 4 rows
  const int rzb = blk >> 3;
  const int z   = rzb % D1;
  const int b   = rzb / D1;
  const int y0  = yt * 4;

  int st_r[5], st_base[5];
  #pragma unroll
  for (int it = 0; it < 5; ++it) {
    int g = it*256 + tid; g = g > 1055 ? 1055 : g;   // 1056 = 4 rows * 264
    int r = g / 264, rem = g - r*264;
    int v = rem >> 3, c16p = rem & 7;
    int c16l = c16p ^ (v & 7);
    st_r[it] = r;
    st_base[it] = (v << 7) + (c16l << 4);
  }

  const char* xinb = (const char*)xin;

  f32x4 acc[2][4];
  #pragma unroll
  for (int a = 0; a < 2; a++)
    #pragma unroll
    for (int cb = 0; cb < 4; cb++)
      acc[a][cb] = f32x4{0.f, 0.f, 0.f, 0.f};

  auto STAGE = [&](int kzn, int kyn, int hn) {
    size_t pb = (size_t)((b*DP + z + kzn)*DP) * (DP*128);
    char* dst = (char*)&sA[0] + hn*(C23_HALF*16);
    #pragma unroll
    for (int it = 0; it < 5; ++it) {
      int yin = y0 + st_r[it] + kyn; yin = yin > 32 ? 32 : yin;
      __builtin_amdgcn_global_load_lds(
        (const __attribute__((address_space(1))) void*)(xinb + pb + (size_t)yin*(DP*128) + st_base[it]),
        (__attribute__((address_space(3))) void*)(dst + it*4096 + wid*1024),
        16, 0, 0);
    }
  };
  auto LDA = [&](int hh, int kx, int kk, short8 (&A)[2]) {
    #pragma unroll
    for (int a = 0; a < 2; a++) {
      int xv = a*16 + ll; xv = xv > 30 ? 30 : xv;   // x=31 duplicated, discarded
      int v  = xv + kx;
      int ch = hh*C23_HALF + wid*264 + v*8 + ((kk*4 + l16) ^ (v & 7));
      A[a] = sA[ch];
    }
  };

  short8 A0[2], A1[2];

  STAGE(0, 0, 0);
  __syncthreads();

  int kzn = 0, kyn = 1;
  #pragma unroll 1
  for (int p = 0; p < 9; ++p) {
    const int hh = p & 1;

    short8 W[6][4];
    {
      const unsigned short* wp = wB + (size_t)p*12288 + lane*8;
      #pragma unroll
      for (int st = 0; st < 6; ++st)
        #pragma unroll
        for (int cb = 0; cb < 4; cb++)
          W[st][cb] = *reinterpret_cast<const short8*>(wp + st*2048 + cb*512);
    }
    __builtin_amdgcn_sched_barrier(0);

    if (p < 8) {
      STAGE(kzn, kyn, hh ^ 1);
      kyn++; if (kyn == 3) { kyn = 0; kzn++; }
    }
    __builtin_amdgcn_sched_barrier(0);

    LDA(hh, 0, 0, A0);
    #pragma unroll
    for (int st = 0; st < 6; ++st) {
      const int kxn = (st+1) >> 1, kkn = (st+1) & 1;
      if (st < 5) {
        if (st & 1) LDA(hh, kxn, kkn, A0); else LDA(hh, kxn, kkn, A1);
      }
      if (st & 1) c_step2(A1, W[st], acc); else c_step2(A0, W[st], acc);
    }
    __syncthreads();
  }

  const int y = y0 + wid;
  if (y < D1) {
    #pragma unroll
    for (int a = 0; a < 2; a++) {
      int x = a*16 + ll;
      if (x >= D1) continue;
      size_t pOff = (size_t)(((b*DP + z+1)*DP + y+1)*DP + (x+1));
      bool m = m1p[pOff] > 0.f;
      #pragma unroll
      for (int cb = 0; cb < 4; cb++) {
        unsigned long long pack = 0;
        #pragma unroll
        for (int r = 0; r < 4; r++) {
          int co = cb*16 + l16*4 + r;
          float o = m ? fmaxf((acc[a][cb][r] + bias[co])*s[co] + h[co], 0.f) : 0.f;
          pack |= (unsigned long long)f2bf(o) << (16*r);
        }
        *reinterpret_cast<unsigned long long*>(xout + pOff*64 + cb*16 + l16*4) = pack;
      }
    }
  }
}

// ---------------- convT v3: single-shot LDS stage + fused in-kernel mask ----------------
constexpr int CT_CHUNKS = 1792;   // 7 iters * 256 threads; 1584 used + pad

__global__ void __launch_bounds__(256)
k_convT_mfma(const unsigned short* __restrict__ x3, const unsigned short* __restrict__ wB,
             unsigned short* __restrict__ x4, const float* __restrict__ m1p,
             const float* __restrict__ bias, const float* __restrict__ s,
             const float* __restrict__ h) {
  __shared__ short8 sb[CT_CHUNKS];
  __shared__ float sMask[4*64];
  const int tid  = threadIdx.x;
  const int lane = tid & 63;
  const int wid  = tid >> 6;
  const int ii   = lane & 15;
  const int l16  = lane >> 4;

  const int blk   = xcd_swz(blockIdx.x, gridDim.x);
  const int ytile = blk & 15;
  const int rzb   = blk >> 4;
  const int zo    = rzb % D4;
  const int b     = rzb / D4;
  const int y0    = ytile * 4;

  const int izp0 = (zo + (zo & 1)) >> 1;
  const int izp1 = (zo & 1) ? izp0 : izp0 + 1;

  #pragma unroll
  for (int it = 0; it < 7; ++it) {
    int g = it*256 + tid; g = g > 1583 ? 1583 : g;
    int r6 = g / 264, rem = g - r6*264;
    int v = rem >> 3, c16p = rem & 7;
    int c16l = c16p ^ (v & 7);
    int pz  = r6 >= 3 ? 1 : 0;
    int ry  = r6 - pz*3;
    int izp = pz ? izp1 : izp0;
    int iyp = ytile*2 + ry;
    size_t srcB = ((size_t)((b*DP + izp)*DP + iyp)*DP)*128 + (size_t)(v << 7) + (c16l << 4);
    __builtin_amdgcn_global_load_lds(
      (const __attribute__((address_space(1))) void*)((const char*)x3 + srcB),
      (__attribute__((address_space(3))) void*)((char*)&sb[0] + it*4096 + wid*1024),
      16, 0, 0);
  }

  // fused mask: wave wid computes its own row's mT[xo] (overlaps the DMA wait)
  {
    const int yo_m = y0 + wid;               // yo=63 computes garbage, unused
    const int xo_m = lane > 62 ? 62 : lane;
    float mm = 0.f;
    #pragma unroll
    for (int kz = 0; kz < 3; kz++) {
      if ((zo + kz) & 1) continue;
      int izp = ((zo + kz - 2) >> 1) + 1;
      #pragma unroll
      for (int ky = 0; ky < 3; ky++) {
        if ((yo_m + ky) & 1) continue;
        int iyp = ((yo_m + ky - 2) >> 1) + 1;
        #pragma unroll
        for (int kx = 0; kx < 3; kx++) {
          if ((xo_m + kx) & 1) continue;
          int ixp = ((xo_m + kx - 2) >> 1) + 1;
          mm += m1p[((b*DP + izp)*DP + iyp)*DP + ixp];
        }
      }
    }
    sMask[wid*64 + lane] = mm;
  }
  __syncthreads();

  f32x4 acc[4][4];
  #pragma unroll
  for (int a = 0; a < 4; a++)
    #pragma unroll
    for (int cb = 0; cb < 4; cb++)
      acc[a][cb] = f32x4{0.f, 0.f, 0.f, 0.f};

  const int yo = y0 + wid;
  if (yo < D4) {
    const int nPz = (zo & 1) ? 1 : 2;
    #pragma unroll 1
    for (int pz = 0; pz < 2; ++pz) {
      if (pz >= nPz) break;
      const int kz = (zo & 1) ? 1 : pz*2;
      #pragma unroll 1
      for (int kyi = 0; kyi < 2; ++kyi) {
        int ky, ry;
        if (wid & 1) { if (kyi == 1) break; ky = 1; ry = (wid + 1) >> 1; }
        else         { ky = kyi*2;          ry = (wid >> 1) + kyi; }
        const int rbase = (pz*3 + ry)*264;
        #pragma unroll
        for (int kx = 0; kx < 3; ++kx) {
          const int apar  = kx & 1;
          const int xoffE = ((kx + apar - 2) >> 1) + 1;
          const int t = (kz*3 + ky)*3 + kx;
          #pragma unroll
          for (int kk = 0; kk < 2; ++kk) {
            short8 Bv[4];
            const unsigned short* wpk = wB + (size_t)(t*2+kk)*2048 + lane*8;
            #pragma unroll
            for (int cb = 0; cb < 4; cb++)
              Bv[cb] = *reinterpret_cast<const short8*>(wpk + cb*512);
            #pragma unroll
            for (int ablk = 0; ablk < 2; ablk++) {
              const int ixp = ablk*16 + ii + xoffE;
              short8 A = sb[rbase + ixp*8 + ((kk*4 + l16) ^ (ixp & 7))];
              const int afr = apar*2 + ablk;
              #pragma unroll
              for (int cb = 0; cb < 4; cb++)
                acc[afr][cb] = __builtin_amdgcn_mfma_f32_16x16x32_bf16(A, Bv[cb], acc[afr][cb], 0, 0, 0);
            }
          }
        }
      }
    }

    float bv[4], sv[4], hv[4];
    #pragma unroll
    for (int cb = 0; cb < 4; cb++) {
      int c = cb*16 + (lane & 15);
      bv[cb] = bias[c]; sv[cb] = s[c]; hv[cb] = h[c];
    }
    const int rowBase = ((b*D4 + zo)*D4 + yo)*D4;
    #pragma unroll
    for (int a = 0; a < 4; a++) {
      const int ablk = a & 1, apar = a >> 1;
      #pragma unroll
      for (int r = 0; r < 4; r++) {
        const int row = (lane >> 4)*4 + r;
        const int xo  = 2*(ablk*16 + row) + apar;
        if (xo >= D4) continue;
        const int vox = rowBase + xo;
        const bool m = sMask[wid*64 + xo] > 0.f;
        #pragma unroll
        for (int cb = 0; cb < 4; cb++) {
          float o = m ? fmaxf((acc[a][cb][r] + bv[cb])*sv[cb] + hv[cb], 0.f) : 0.f;
          x4[(size_t)vox*64 + cb*16 + (lane & 15)] = f2bf(o);
        }
      }
    }
  }
}

// ---------------- conv5 v12: barrier-free per-wave async pipeline (131us; kept) ----------------
constexpr int C5_WSLOT = 544;   // chunks per wave-half: 504 used + overflow pad

__global__ void __launch_bounds__(256, 2)
k_conv5_mfma(const unsigned short* __restrict__ x4, const unsigned short* __restrict__ wB,
             float* __restrict__ out, const float* __restrict__ bias,
             const float* __restrict__ s, const float* __restrict__ h) {
  __shared__ short8 sA[2*4*C5_WSLOT];   // 68KB
  const int tid  = threadIdx.x;
  const int lane = tid & 63;
  const int wid  = tid >> 6;
  const int ll   = lane & 15;
  const int l16  = lane >> 4;

  const int blk   = xcd_swz(blockIdx.x, gridDim.x);
  const int ytile = blk & 15;
  const int rzb   = blk >> 4;
  const int z     = rzb % D5;
  const int b     = rzb / D5;
  const int y0    = ytile * 4;

  int st_off[8];
  #pragma unroll
  for (int it = 0; it < 8; ++it) {
    int g = it*64 + lane; g = g > 503 ? 503 : g;
    int v = g >> 3, c16p = g & 7;
    int c16l = c16p ^ (v & 7);
    st_off[it] = (v << 7) + (c16l << 4);
  }

  const char* x4b = (const char*)x4;

  f32x4 acc[4][4];
  #pragma unroll
  for (int a = 0; a < 4; a++)
    #pragma unroll
    for (int cb = 0; cb < 4; cb++)
      acc[a][cb] = f32x4{0.f, 0.f, 0.f, 0.f};

  auto STAGE = [&](int kzn, int kyn, int hn) {
    int yin = y0 + wid + kyn; yin = yin > 62 ? 62 : yin;
    size_t rb = ((size_t)((b*D4 + z + kzn)*D4 + yin)) * 8064;
    char* dst = (char*)&sA[0] + (size_t)(hn*4 + wid)*(C5_WSLOT*16);
    #pragma unroll
    for (int it = 0; it < 8; ++it) {
      __builtin_amdgcn_global_load_lds(
        (const __attribute__((address_space(1))) void*)(x4b + rb + st_off[it]),
        (__attribute__((address_space(3))) void*)(dst + it*1024),
        16, 0, 0);
    }
  };
  auto LDA = [&](int hh, int kx, int kk, short8 (&A)[4]) {
    #pragma unroll
    for (int a = 0; a < 4; a++) {
      int v  = a*16 + ll + kx;
      int ch = (hh*4 + wid)*C5_WSLOT + v*8 + ((kk*4 + l16) ^ (v & 7));
      A[a] = sA[ch];
    }
  };

  short8 A0[4], A1[4], A2[4];

  STAGE(0, 0, 0);

#define C5_BODY(p0,p1,p2,p3,p4,p5)                                    \
  do {                                                                 \
    LDA(hh, (p0)>>1, (p0)&1, A0);                                      \
    LDA(hh, (p1)>>1, (p1)&1, A1);                                      \
    LDA(hh, (p2)>>1, (p2)&1, A2);  c5_step(A0, W[p0], acc);            \
    LDA(hh, (p3)>>1, (p3)&1, A0);  c5_step(A1, W[p1], acc);            \
    LDA(hh, (p4)>>1, (p4)&1, A1);  c5_step(A2, W[p2], acc);            \
    LDA(hh, (p5)>>1, (p5)&1, A2);  c5_step(A0, W[p3], acc);            \
    c5_step(A1, W[p4], acc);                                           \
    c5_step(A2, W[p5], acc);                                           \
  } while (0)

  int kzn = 0, kyn = 1;
  #pragma unroll 1
  for (int p = 0; p < 9; ++p) {
    const int hh = p & 1;

    short8 W[6][4];
    {
      const unsigned short* wp = wB + (size_t)p*12288 + lane*8;
      #pragma unroll
      for (int st = 0; st < 6; ++st)
        #pragma unroll
        for (int cb = 0; cb < 4; cb++)
          W[st][cb] = *reinterpret_cast<const short8*>(wp + st*2048 + cb*512);
    }
    __builtin_amdgcn_sched_barrier(0);

    if (p < 8) {
      STAGE(kzn, kyn, hh ^ 1);
      kyn++; if (kyn == 3) { kyn = 0; kzn++; }
    } else {
      STAGE(2, 2, hh ^ 1);                 // dummy: keeps vmcnt count uniform
    }
    __builtin_amdgcn_sched_barrier(0);

    asm volatile("s_waitcnt vmcnt(8)" ::: "memory");
    __builtin_amdgcn_sched_barrier(0);

    C5_BODY(0,1,2,3,4,5);
  }
#undef C5_BODY

  const int yout = y0 + wid;
  if (yout < D5) {
    #pragma unroll
    for (int a = 0; a < 4; a++) {
      int x = a*16 + ll;
      if (x >= D5) continue;
      size_t sp = (size_t)(z*D5 + yout)*D5 + x;
      #pragma unroll
      for (int cb = 0; cb < 4; cb++)
        #pragma unroll
        for (int r = 0; r < 4; r++) {
          int co = cb*16 + l16*4 + r;
          float o = fmaxf((acc[a][cb][r] + bias[co])*s[co] + h[co], 0.f);
          out[(size_t)(b*64 + co)*D5CUBE + sp] = o;
        }
    }
  }
}

// ---------------- launcher ----------------
extern "C" void kernel_launch(void* const* d_in, const int* in_sizes, int n_in,
                              void* d_out, int out_size, void* d_ws, size_t ws_size,
                              hipStream_t stream) {
  const float* feat  = (const float*)d_in[0];
  const int*   coors = (const int*)d_in[1];
  const float* w1 = (const float*)d_in[3];
  const float* b1 = (const float*)d_in[4];
  const float* w2 = (const float*)d_in[5];
  const float* b2 = (const float*)d_in[6];
  const float* w3 = (const float*)d_in[7];
  const float* b3 = (const float*)d_in[8];
  const float* wt = (const float*)d_in[9];
  const float* bt = (const float*)d_in[10];
  const float* w5 = (const float*)d_in[11];
  const float* b5 = (const float*)d_in[12];
  const float* s1 = (const float*)d_in[13];
  const float* h1 = (const float*)d_in[14];
  const float* s2 = (const float*)d_in[15];
  const float* h2 = (const float*)d_in[16];
  const float* s3 = (const float*)d_in[17];
  const float* h3 = (const float*)d_in[18];
  const float* s4 = (const float*)d_in[19];
  const float* h4 = (const float*)d_in[20];
  const float* s5 = (const float*)d_in[21];
  const float* h5 = (const float*)d_in[22];
  int n = in_sizes[0] / 3;

  char* wsb = (char*)d_ws;
  float*          X0  = (float*)(wsb + OB_X0);
  float*          M0  = (float*)(wsb + OB_M0);
  float*          M1P = (float*)(wsb + OB_M1P);
  unsigned short* X1  = (unsigned short*)(wsb + OB_X1);
  unsigned short* X2  = (unsigned short*)(wsb + OB_X2);
  unsigned short* X3  = (unsigned short*)(wsb + OB_X3);
  unsigned short* X4  = (unsigned short*)(wsb + OB_X4);
  unsigned short* WB2 = (unsigned short*)(wsb + OB_WB2);
  unsigned short* WB3 = (unsigned short*)(wsb + OB_WB3);
  unsigned short* WBT = (unsigned short*)(wsb + OB_WBT);
  unsigned short* WB5 = (unsigned short*)(wsb + OB_WB5);

  k_setup<<<SETUP_ZBLK + 1728, 256, 0, stream>>>(X0, M0, M1P, X1, X2, X3,
                                                 w2, w3, wt, w5, WB2, WB3, WBT, WB5);

  k_scatter<<<(n+255)/256, 256, 0, stream>>>(feat, coors, n, X0, M0);

  {
    long long threads = (long long)NV1*C;
    k_conv1<<<(int)((threads+255)/256), 256, 0, stream>>>(X0, M0, X1, M1P, w1, b1, s1, h1);
  }

  constexpr int BLK23 = BB * D1 * 8;              // 496 blocks (b, z, ytile)
  k_conv23_mfma<<<BLK23, 256, 0, stream>>>(X1, WB2, X2, M1P, b2, s2, h2);
  k_conv23_mfma<<<BLK23, 256, 0, stream>>>(X2, WB3, X3, M1P, b3, s3, h3);

  constexpr int BLK_T = BB * D4 * 16;             // 2016 blocks (b, zo, ytile)
  k_convT_mfma<<<BLK_T, 256, 0, stream>>>(X3, WBT, X4, M1P, bt, s4, h4);

  constexpr int BLK5 = BB * D5 * 16;              // 1952 blocks (b, z, ytile)
  k_conv5_mfma<<<BLK5, 256, 0, stream>>>(X4, WB5, (float*)d_out, b5, s5, h5);
}